// Round 2
// baseline (1609.841 us; speedup 1.0000x reference)
//
#include <hip/hip_runtime.h>

#define D 128

static inline int cdiv(int a, int b){ return (a + b - 1) / b; }

// ---------------- degree / CSR build ----------------

__global__ __launch_bounds__(256) void zero_cnt_kernel(int* __restrict__ cnt_out,
                                                       int* __restrict__ cnt_in, int n)
{
    int i = blockIdx.x * 256 + threadIdx.x;
    if (i < n) { cnt_out[i] = 0; cnt_in[i] = 0; }
}

__global__ __launch_bounds__(256) void count_kernel(const int* __restrict__ src,
                                                    const int* __restrict__ dst,
                                                    int* __restrict__ cnt_out,
                                                    int* __restrict__ cnt_in, int E)
{
    int i = blockIdx.x * 256 + threadIdx.x;
    if (i < E) {
        atomicAdd(&cnt_out[src[i]], 1);
        atomicAdd(&cnt_in[dst[i]], 1);
    }
}

__global__ __launch_bounds__(256) void dinv_kernel(const int* __restrict__ cnt_out,
                                                   const int* __restrict__ cnt_in,
                                                   float* __restrict__ dinv_out,
                                                   float* __restrict__ dinv_in, int n)
{
    int i = blockIdx.x * 256 + threadIdx.x;
    if (i < n) {
        dinv_out[i] = rsqrtf(fmaxf((float)cnt_out[i], 1.0f));
        dinv_in[i]  = rsqrtf(fmaxf((float)cnt_in[i],  1.0f));
    }
}

// exclusive scan, stage 1: per-1024-chunk partial exclusive prefix + chunk totals
__global__ __launch_bounds__(256) void scan_partial(const int* __restrict__ cnt,
                                                    int* __restrict__ pre,
                                                    int* __restrict__ blk_sums, int n)
{
    __shared__ int lds[256];
    int t = threadIdx.x;
    int base = blockIdx.x * 1024 + t * 4;
    int v0 = 0, v1 = 0, v2 = 0, v3 = 0;
    if (base + 0 < n) v0 = cnt[base + 0];
    if (base + 1 < n) v1 = cnt[base + 1];
    if (base + 2 < n) v2 = cnt[base + 2];
    if (base + 3 < n) v3 = cnt[base + 3];
    int ts = v0 + v1 + v2 + v3;
    lds[t] = ts;
    __syncthreads();
    for (int off = 1; off < 256; off <<= 1) {
        int add = (t >= off) ? lds[t - off] : 0;
        __syncthreads();
        lds[t] += add;
        __syncthreads();
    }
    int excl = lds[t] - ts;
    if (base + 0 < n) pre[base + 0] = excl;
    if (base + 1 < n) pre[base + 1] = excl + v0;
    if (base + 2 < n) pre[base + 2] = excl + v0 + v1;
    if (base + 3 < n) pre[base + 3] = excl + v0 + v1 + v2;
    if (t == 255) blk_sums[blockIdx.x] = lds[255];
}

// stage 2: serial scan of chunk totals (<=4096 chunks, trivial)
__global__ void scan_blk(const int* __restrict__ blk_sums, int* __restrict__ blk_off, int nblk)
{
    if (threadIdx.x == 0 && blockIdx.x == 0) {
        int run = 0;
        for (int j = 0; j < nblk; ++j) { blk_off[j] = run; run += blk_sums[j]; }
    }
}

// stage 3: combine, write row_start + fill cursor
__global__ __launch_bounds__(256) void scan_final(const int* __restrict__ pre,
                                                  const int* __restrict__ blk_off,
                                                  int* __restrict__ row_start,
                                                  int* __restrict__ fill_ptr, int n, int E)
{
    int i = blockIdx.x * 256 + threadIdx.x;
    if (i < n) {
        int v = pre[i] + blk_off[i >> 10];
        row_start[i] = v;
        fill_ptr[i]  = v;
    }
    if (i == 0) row_start[n] = E;
}

__global__ __launch_bounds__(256) void fill_kernel(const int* __restrict__ src,
                                                   const int* __restrict__ dst,
                                                   int* __restrict__ fill_ptr,
                                                   int* __restrict__ esrc, int E)
{
    int i = blockIdx.x * 256 + threadIdx.x;
    if (i < E) {
        int p = atomicAdd(&fill_ptr[dst[i]], 1);
        esrc[p] = src[i];
    }
}

// ---------------- graph conv: one wave per destination node (no atomics) ----------------
// hout[v] = dinv_in[v] * sum_{e: dst=v} hin[src_e] * dinv_out[src_e]
// rep[v] += gamma[lidx] * hout[v]
__global__ __launch_bounds__(256, 4) void conv_kernel(const float* __restrict__ hin,
                                                      float* __restrict__ hout,
                                                      float* __restrict__ rep,
                                                      const int* __restrict__ row_start,
                                                      const int* __restrict__ esrc,
                                                      const float* __restrict__ dinv_out,
                                                      const float* __restrict__ dinv_in,
                                                      const float* __restrict__ gamma,
                                                      int lidx, int n)
{
    int wid  = (blockIdx.x * 256 + threadIdx.x) >> 6;   // node index (wave)
    int lane = threadIdx.x & 63;                        // 2 dims per lane via float2
    if (wid >= n) return;
    int rs = row_start[wid];
    int re = row_start[wid + 1];
    const float2* hb = (const float2*)hin;
    float ax = 0.f, ay = 0.f;
    for (int i = rs; i < re; ++i) {
        int s = esrc[i];
        float sc = dinv_out[s];
        float2 v = hb[(size_t)s * 64 + lane];
        ax += v.x * sc;
        ay += v.y * sc;
    }
    float di = dinv_in[wid];
    float g  = gamma[lidx];
    float2 h; h.x = ax * di; h.y = ay * di;
    ((float2*)hout)[(size_t)wid * 64 + lane] = h;
    float2* rp = (float2*)rep + (size_t)wid * 64 + lane;
    float2 r = *rp;
    r.x += g * h.x;
    r.y += g * h.y;
    *rp = r;
}

// ---------------- row-per-lane 128x128 dense layers ----------------
// MODE 0: lin1      : in = X[row],              out = relu(acc)
// MODE 1: lin2      : in = X[row],              out = acc ; rep = gamma[0]*acc
// MODE 2: predictor1: in = X[ia[row]]*X[ib[row]], out = relu(acc)
// MODE 3: pred2+3   : in = X[row], e2 = relu(acc), outsc[row] = dot(e2,w3)+b3
template<int MODE>
__global__ __launch_bounds__(256, 2) void mlp128(const float* __restrict__ X,
                                                 const float* __restrict__ W,
                                                 const float* __restrict__ B,
                                                 float* __restrict__ out, int nrows,
                                                 const float* __restrict__ gamma,
                                                 float* __restrict__ rep,
                                                 const int* __restrict__ ia,
                                                 const int* __restrict__ ib,
                                                 const float* __restrict__ w3,
                                                 const float* __restrict__ b3,
                                                 float* __restrict__ outsc)
{
    int row = blockIdx.x * 256 + threadIdx.x;
    if (row >= nrows) return;

    float acc[D];
    #pragma unroll
    for (int c = 0; c < D; ++c) acc[c] = B[c];

    size_t rb = (size_t)row * D;

    if (MODE == 2) {
        const float4* pa = (const float4*)(X + (size_t)ia[row] * D);
        const float4* pb = (const float4*)(X + (size_t)ib[row] * D);
        #pragma unroll 1
        for (int k4 = 0; k4 < D / 4; ++k4) {
            float4 va = pa[k4];
            float4 vb = pb[k4];
            float x0 = va.x * vb.x, x1 = va.y * vb.y, x2 = va.z * vb.z, x3 = va.w * vb.w;
            const float* wr = W + (size_t)k4 * 4 * D;
            #pragma unroll
            for (int c = 0; c < D; ++c) acc[c] += x0 * wr[c];
            #pragma unroll
            for (int c = 0; c < D; ++c) acc[c] += x1 * wr[D + c];
            #pragma unroll
            for (int c = 0; c < D; ++c) acc[c] += x2 * wr[2 * D + c];
            #pragma unroll
            for (int c = 0; c < D; ++c) acc[c] += x3 * wr[3 * D + c];
        }
    } else {
        const float4* px = (const float4*)(X + rb);
        #pragma unroll 1
        for (int k4 = 0; k4 < D / 4; ++k4) {
            float4 v = px[k4];
            const float* wr = W + (size_t)k4 * 4 * D;
            #pragma unroll
            for (int c = 0; c < D; ++c) acc[c] += v.x * wr[c];
            #pragma unroll
            for (int c = 0; c < D; ++c) acc[c] += v.y * wr[D + c];
            #pragma unroll
            for (int c = 0; c < D; ++c) acc[c] += v.z * wr[2 * D + c];
            #pragma unroll
            for (int c = 0; c < D; ++c) acc[c] += v.w * wr[3 * D + c];
        }
    }

    if (MODE == 0 || MODE == 2) {
        float4* po = (float4*)(out + rb);
        #pragma unroll
        for (int c4 = 0; c4 < D / 4; ++c4) {
            float4 o;
            o.x = fmaxf(acc[4 * c4 + 0], 0.f);
            o.y = fmaxf(acc[4 * c4 + 1], 0.f);
            o.z = fmaxf(acc[4 * c4 + 2], 0.f);
            o.w = fmaxf(acc[4 * c4 + 3], 0.f);
            po[c4] = o;
        }
    } else if (MODE == 1) {
        float g0 = gamma[0];
        float4* po = (float4*)(out + rb);
        float4* pr = (float4*)(rep + rb);
        #pragma unroll
        for (int c4 = 0; c4 < D / 4; ++c4) {
            float4 o;
            o.x = acc[4 * c4 + 0]; o.y = acc[4 * c4 + 1];
            o.z = acc[4 * c4 + 2]; o.w = acc[4 * c4 + 3];
            po[c4] = o;
            float4 r;
            r.x = g0 * o.x; r.y = g0 * o.y; r.z = g0 * o.z; r.w = g0 * o.w;
            pr[c4] = r;
        }
    } else { // MODE 3
        float s = b3[0];
        #pragma unroll
        for (int c = 0; c < D; ++c) s += fmaxf(acc[c], 0.f) * w3[c];
        outsc[row] = s;
    }
}

// ---------------- launcher ----------------

extern "C" void kernel_launch(void* const* d_in, const int* in_sizes, int n_in,
                              void* d_out, int out_size, void* d_ws, size_t ws_size,
                              hipStream_t stream)
{
    const float* x      = (const float*)d_in[0];
    const float* lin1_w = (const float*)d_in[1];
    const float* lin1_b = (const float*)d_in[2];
    const float* lin2_w = (const float*)d_in[3];
    const float* lin2_b = (const float*)d_in[4];
    const float* gamma  = (const float*)d_in[5];
    const float* p1_w   = (const float*)d_in[6];
    const float* p1_b   = (const float*)d_in[7];
    const float* p2_w   = (const float*)d_in[8];
    const float* p2_b   = (const float*)d_in[9];
    const float* p3_w   = (const float*)d_in[10];
    const float* p3_b   = (const float*)d_in[11];
    const int* src     = (const int*)d_in[12];
    const int* dst     = (const int*)d_in[13];
    const int* pos_src = (const int*)d_in[14];
    const int* pos_dst = (const int*)d_in[15];
    const int* neg_src = (const int*)d_in[16];
    const int* neg_dst = (const int*)d_in[17];

    const int N = in_sizes[0] / D;
    const int E = in_sizes[12];
    const int P = in_sizes[14];

    // workspace layout
    float* ws = (float*)d_ws;
    size_t fN = (size_t)N * D;
    float* bufB = ws;            // h1 / conv outputs (ping)
    float* bufA = ws + fN;       // h0 / conv outputs (pong)
    float* rep  = ws + 2 * fN;   // gamma-weighted accumulation
    char* ip = (char*)(ws + 3 * fN);
    int* cnt_out   = (int*)ip;  ip += (size_t)N * 4;
    int* cnt_in    = (int*)ip;  ip += (size_t)N * 4;
    int* pre       = (int*)ip;  ip += (size_t)N * 4;
    int* row_start = (int*)ip;  ip += (size_t)(N + 1) * 4;
    int* fill_ptr  = (int*)ip;  ip += (size_t)N * 4;
    int* blk_sums  = (int*)ip;  ip += 4096 * 4;
    int* blk_off   = (int*)ip;  ip += 4096 * 4;
    float* dinv_out = (float*)ip; ip += (size_t)N * 4;
    float* dinv_in  = (float*)ip; ip += (size_t)N * 4;
    int* esrc      = (int*)ip;  ip += (size_t)E * 4;
    // e1 [2P x D] overlaps bufA+bufB (dead after conv3) when it fits, else appended
    float* e1;
    if ((size_t)(2 * P) * D <= 2 * fN) {
        e1 = ws;
    } else {
        e1 = (float*)ip; ip += (size_t)(2 * P) * D * 4;
    }

    // ---- degrees + CSR (by dst) ----
    zero_cnt_kernel<<<cdiv(N, 256), 256, 0, stream>>>(cnt_out, cnt_in, N);
    count_kernel<<<cdiv(E, 256), 256, 0, stream>>>(src, dst, cnt_out, cnt_in, E);
    dinv_kernel<<<cdiv(N, 256), 256, 0, stream>>>(cnt_out, cnt_in, dinv_out, dinv_in, N);
    int nblk = cdiv(N, 1024);
    scan_partial<<<nblk, 256, 0, stream>>>(cnt_in, pre, blk_sums, N);
    scan_blk<<<1, 64, 0, stream>>>(blk_sums, blk_off, nblk);
    scan_final<<<cdiv(N, 256), 256, 0, stream>>>(pre, blk_off, row_start, fill_ptr, N, E);
    fill_kernel<<<cdiv(E, 256), 256, 0, stream>>>(src, dst, fill_ptr, esrc, E);

    // ---- node MLP: h1 = relu(x@W1+b1); h0 = h1@W2+b2; rep = gamma0*h0 ----
    mlp128<0><<<cdiv(N, 256), 256, 0, stream>>>(x, lin1_w, lin1_b, bufB, N,
        nullptr, nullptr, nullptr, nullptr, nullptr, nullptr, nullptr);
    mlp128<1><<<cdiv(N, 256), 256, 0, stream>>>(bufB, lin2_w, lin2_b, bufA, N,
        gamma, rep, nullptr, nullptr, nullptr, nullptr, nullptr);

    // ---- 3 propagation layers, rep += gamma[l]*h_l ----
    conv_kernel<<<cdiv(N, 4), 256, 0, stream>>>(bufA, bufB, rep, row_start, esrc,
                                                dinv_out, dinv_in, gamma, 1, N);
    conv_kernel<<<cdiv(N, 4), 256, 0, stream>>>(bufB, bufA, rep, row_start, esrc,
                                                dinv_out, dinv_in, gamma, 2, N);
    conv_kernel<<<cdiv(N, 4), 256, 0, stream>>>(bufA, bufB, rep, row_start, esrc,
                                                dinv_out, dinv_in, gamma, 3, N);

    // ---- predictor: e1 = relu((rep[a]*rep[b])@P1+b1); out = relu(e1@P2+b2)@P3+b3 ----
    mlp128<2><<<cdiv(P, 256), 256, 0, stream>>>(rep, p1_w, p1_b, e1, P,
        nullptr, nullptr, pos_src, pos_dst, nullptr, nullptr, nullptr);
    mlp128<2><<<cdiv(P, 256), 256, 0, stream>>>(rep, p1_w, p1_b, e1 + (size_t)P * D, P,
        nullptr, nullptr, neg_src, neg_dst, nullptr, nullptr, nullptr);
    mlp128<3><<<cdiv(2 * P, 256), 256, 0, stream>>>(e1, p2_w, p2_b, nullptr, 2 * P,
        nullptr, nullptr, nullptr, nullptr, p3_w, p3_b, (float*)d_out);
}

// Round 4
// 1314.465 us; speedup vs baseline: 1.2247x; 1.2247x over previous
//
#include <hip/hip_runtime.h>

#define D 128
#define BM 128
#define BK 16
#define LDP (BM + 4)

static inline int cdiv(int a, int b){ return (a + b - 1) / b; }

// ---------------- degree / CSR build ----------------

__global__ __launch_bounds__(256) void zero_cnt_kernel(int* __restrict__ cnt_out,
                                                       int* __restrict__ cnt_in, int n)
{
    int i = blockIdx.x * 256 + threadIdx.x;
    if (i < n) { cnt_out[i] = 0; cnt_in[i] = 0; }
}

__global__ __launch_bounds__(256) void count_kernel(const int* __restrict__ src,
                                                    const int* __restrict__ dst,
                                                    int* __restrict__ cnt_out,
                                                    int* __restrict__ cnt_in, int E)
{
    int i = blockIdx.x * 256 + threadIdx.x;
    if (i < E) {
        atomicAdd(&cnt_out[src[i]], 1);
        atomicAdd(&cnt_in[dst[i]], 1);
    }
}

__global__ __launch_bounds__(256) void dinv_kernel(const int* __restrict__ cnt_out,
                                                   const int* __restrict__ cnt_in,
                                                   float* __restrict__ dinv_out,
                                                   float* __restrict__ dinv_in, int n)
{
    int i = blockIdx.x * 256 + threadIdx.x;
    if (i < n) {
        dinv_out[i] = rsqrtf(fmaxf((float)cnt_out[i], 1.0f));
        dinv_in[i]  = rsqrtf(fmaxf((float)cnt_in[i],  1.0f));
    }
}

__global__ __launch_bounds__(256) void scan_partial(const int* __restrict__ cnt,
                                                    int* __restrict__ pre,
                                                    int* __restrict__ blk_sums, int n)
{
    __shared__ int lds[256];
    int t = threadIdx.x;
    int base = blockIdx.x * 1024 + t * 4;
    int v0 = 0, v1 = 0, v2 = 0, v3 = 0;
    if (base + 0 < n) v0 = cnt[base + 0];
    if (base + 1 < n) v1 = cnt[base + 1];
    if (base + 2 < n) v2 = cnt[base + 2];
    if (base + 3 < n) v3 = cnt[base + 3];
    int ts = v0 + v1 + v2 + v3;
    lds[t] = ts;
    __syncthreads();
    for (int off = 1; off < 256; off <<= 1) {
        int add = (t >= off) ? lds[t - off] : 0;
        __syncthreads();
        lds[t] += add;
        __syncthreads();
    }
    int excl = lds[t] - ts;
    if (base + 0 < n) pre[base + 0] = excl;
    if (base + 1 < n) pre[base + 1] = excl + v0;
    if (base + 2 < n) pre[base + 2] = excl + v0 + v1;
    if (base + 3 < n) pre[base + 3] = excl + v0 + v1 + v2;
    if (t == 255) blk_sums[blockIdx.x] = lds[255];
}

__global__ void scan_blk(const int* __restrict__ blk_sums, int* __restrict__ blk_off, int nblk)
{
    if (threadIdx.x == 0 && blockIdx.x == 0) {
        int run = 0;
        for (int j = 0; j < nblk; ++j) { blk_off[j] = run; run += blk_sums[j]; }
    }
}

__global__ __launch_bounds__(256) void scan_final(const int* __restrict__ pre,
                                                  const int* __restrict__ blk_off,
                                                  int* __restrict__ row_start,
                                                  int* __restrict__ fill_ptr, int n, int E)
{
    int i = blockIdx.x * 256 + threadIdx.x;
    if (i < n) {
        int v = pre[i] + blk_off[i >> 10];
        row_start[i] = v;
        fill_ptr[i]  = v;
    }
    if (i == 0) row_start[n] = E;
}

__global__ __launch_bounds__(256) void fill_kernel(const int* __restrict__ src,
                                                   const int* __restrict__ dst,
                                                   int* __restrict__ fill_ptr,
                                                   int* __restrict__ esrc, int E)
{
    int i = blockIdx.x * 256 + threadIdx.x;
    if (i < E) {
        int p = atomicAdd(&fill_ptr[dst[i]], 1);
        esrc[p] = src[i];
    }
}

// ---------------- graph conv: one wave per destination node (no atomics) ----------------
__global__ __launch_bounds__(256, 4) void conv_kernel(const float* __restrict__ hin,
                                                      float* __restrict__ hout,
                                                      float* __restrict__ rep,
                                                      const int* __restrict__ row_start,
                                                      const int* __restrict__ esrc,
                                                      const float* __restrict__ dinv_out,
                                                      const float* __restrict__ dinv_in,
                                                      const float* __restrict__ gamma,
                                                      int lidx, int n)
{
    int wid  = (blockIdx.x * 256 + threadIdx.x) >> 6;
    int lane = threadIdx.x & 63;
    if (wid >= n) return;
    int rs = row_start[wid];
    int re = row_start[wid + 1];
    const float2* hb = (const float2*)hin;
    float ax = 0.f, ay = 0.f;
    for (int i = rs; i < re; ++i) {
        int s = esrc[i];
        float sc = dinv_out[s];
        float2 v = hb[(size_t)s * 64 + lane];
        ax += v.x * sc;
        ay += v.y * sc;
    }
    float di = dinv_in[wid];
    float g  = gamma[lidx];
    float2 h; h.x = ax * di; h.y = ay * di;
    ((float2*)hout)[(size_t)wid * 64 + lane] = h;
    float2* rp = (float2*)rep + (size_t)wid * 64 + lane;
    float2 r = *rp;
    r.x += g * h.x;
    r.y += g * h.y;
    *rp = r;
}

// ---------------- LDS-tiled f32 GEMM: C[R x 128] = op(A) @ W + b ----------------
// 256 threads -> 128x128 tile, each thread 8 rows x 8 cols in registers.
// MODE 0: A = X[row],                 out = relu(.)
// MODE 1: A = X[row],                 out = .       ; rep = gamma[0]*out
// MODE 2: A = X[ia[row]]*X[ib[row]],  out = relu(.)
// MODE 3: A = X[row], e2 = relu(.),   outsc[row] = dot(e2, w3) + b3
template<int MODE>
__global__ __launch_bounds__(256, 3) void gemm128(const float* __restrict__ X,
                                                  const float* __restrict__ W,
                                                  const float* __restrict__ B,
                                                  float* __restrict__ out, int R,
                                                  const float* __restrict__ gamma,
                                                  float* __restrict__ rep,
                                                  const int* __restrict__ ia,
                                                  const int* __restrict__ ib,
                                                  const float* __restrict__ w3,
                                                  const float* __restrict__ b3,
                                                  float* __restrict__ outsc)
{
    __shared__ float As[BK][LDP];   // transposed A tile: As[k][m]
    __shared__ float Ws[BK][LDP];   // W tile: Ws[k][n]

    const int t  = threadIdx.x;
    const int tc = t & 15;          // col group
    const int tr = t >> 4;          // row group
    const int c0 = tc * 8;
    const int r0 = tr * 8;
    const int rowbase = blockIdx.x * BM;

    // staging coords: A -> thread t covers row (t>>1), k-half (t&1)*8
    const int srow = t >> 1;
    const int skh  = (t & 1) * 8;
    // W -> thread t covers k-row (t>>4), col chunk (t&15)*8
    const int wkr  = t >> 4;
    const int wc   = (t & 15) * 8;

    int arow = rowbase + srow;
    if (arow > R - 1) arow = R - 1;

    const float* aptr;
    const float* bptr2 = nullptr;
    if (MODE == 2) {
        aptr  = X + (size_t)ia[arow] * D;
        bptr2 = X + (size_t)ib[arow] * D;
    } else {
        aptr = X + (size_t)arow * D;
    }

    float acc[8][8];
    #pragma unroll
    for (int i = 0; i < 8; ++i)
        #pragma unroll
        for (int j = 0; j < 8; ++j) acc[i][j] = 0.f;

    // prologue: stage step 0 into registers
    float4 a0, a1, w0, w1;
    {
        const float4* ap = (const float4*)(aptr + skh);
        a0 = ap[0]; a1 = ap[1];
        if (MODE == 2) {
            const float4* bp = (const float4*)(bptr2 + skh);
            float4 q0 = bp[0], q1 = bp[1];
            a0.x *= q0.x; a0.y *= q0.y; a0.z *= q0.z; a0.w *= q0.w;
            a1.x *= q1.x; a1.y *= q1.y; a1.z *= q1.z; a1.w *= q1.w;
        }
        const float4* wp = (const float4*)(W + (size_t)wkr * D + wc);
        w0 = wp[0]; w1 = wp[1];
    }

    #pragma unroll 1
    for (int s = 0; s < D / BK; ++s) {
        __syncthreads();            // prior compute done reading LDS
        // write staged registers -> LDS (A transposed)
        As[skh + 0][srow] = a0.x; As[skh + 1][srow] = a0.y;
        As[skh + 2][srow] = a0.z; As[skh + 3][srow] = a0.w;
        As[skh + 4][srow] = a1.x; As[skh + 5][srow] = a1.y;
        As[skh + 6][srow] = a1.z; As[skh + 7][srow] = a1.w;
        *(float4*)&Ws[wkr][wc]     = w0;
        *(float4*)&Ws[wkr][wc + 4] = w1;
        __syncthreads();
        // prefetch next step (overlaps with compute below)
        if (s + 1 < D / BK) {
            const int k0 = (s + 1) * BK;
            const float4* ap = (const float4*)(aptr + k0 + skh);
            a0 = ap[0]; a1 = ap[1];
            if (MODE == 2) {
                const float4* bp = (const float4*)(bptr2 + k0 + skh);
                float4 q0 = bp[0], q1 = bp[1];
                a0.x *= q0.x; a0.y *= q0.y; a0.z *= q0.z; a0.w *= q0.w;
                a1.x *= q1.x; a1.y *= q1.y; a1.z *= q1.z; a1.w *= q1.w;
            }
            const float4* wp = (const float4*)(W + (size_t)(k0 + wkr) * D + wc);
            w0 = wp[0]; w1 = wp[1];
        }
        // compute this step
        #pragma unroll
        for (int k = 0; k < BK; ++k) {
            float4 av0 = *(const float4*)&As[k][r0];
            float4 av1 = *(const float4*)&As[k][r0 + 4];
            float4 wv0 = *(const float4*)&Ws[k][c0];
            float4 wv1 = *(const float4*)&Ws[k][c0 + 4];
            float af[8] = {av0.x, av0.y, av0.z, av0.w, av1.x, av1.y, av1.z, av1.w};
            float wf[8] = {wv0.x, wv0.y, wv0.z, wv0.w, wv1.x, wv1.y, wv1.z, wv1.w};
            #pragma unroll
            for (int i = 0; i < 8; ++i)
                #pragma unroll
                for (int j = 0; j < 8; ++j)
                    acc[i][j] = fmaf(af[i], wf[j], acc[i][j]);
        }
    }

    // bias for this thread's cols
    float bv[8];
    {
        const float4* bp = (const float4*)(B + c0);
        float4 q0 = bp[0], q1 = bp[1];
        bv[0] = q0.x; bv[1] = q0.y; bv[2] = q0.z; bv[3] = q0.w;
        bv[4] = q1.x; bv[5] = q1.y; bv[6] = q1.z; bv[7] = q1.w;
    }

    if (MODE == 3) {
        float w3v[8];
        const float4* wp = (const float4*)(w3 + c0);
        float4 q0 = wp[0], q1 = wp[1];
        w3v[0] = q0.x; w3v[1] = q0.y; w3v[2] = q0.z; w3v[3] = q0.w;
        w3v[4] = q1.x; w3v[5] = q1.y; w3v[6] = q1.z; w3v[7] = q1.w;
        float part[8];
        #pragma unroll
        for (int i = 0; i < 8; ++i) {
            float s = 0.f;
            #pragma unroll
            for (int j = 0; j < 8; ++j)
                s += fmaxf(acc[i][j] + bv[j], 0.f) * w3v[j];
            part[i] = s;
        }
        #pragma unroll
        for (int m = 1; m < 16; m <<= 1)
            #pragma unroll
            for (int i = 0; i < 8; ++i)
                part[i] += __shfl_xor(part[i], m, 64);
        if (tc == 0) {
            float bb = b3[0];
            #pragma unroll
            for (int i = 0; i < 8; ++i) {
                int r = rowbase + r0 + i;
                if (r < R) outsc[r] = part[i] + bb;
            }
        }
    } else {
        float g0 = (MODE == 1) ? gamma[0] : 0.f;
        #pragma unroll
        for (int i = 0; i < 8; ++i) {
            int r = rowbase + r0 + i;
            if (r < R) {
                float v[8];
                #pragma unroll
                for (int j = 0; j < 8; ++j) {
                    float o = acc[i][j] + bv[j];
                    v[j] = (MODE == 1) ? o : fmaxf(o, 0.f);
                }
                float4* po = (float4*)(out + (size_t)r * D + c0);
                float4 o0; o0.x = v[0]; o0.y = v[1]; o0.z = v[2]; o0.w = v[3];
                float4 o1; o1.x = v[4]; o1.y = v[5]; o1.z = v[6]; o1.w = v[7];
                po[0] = o0; po[1] = o1;
                if (MODE == 1) {
                    float4* pr = (float4*)(rep + (size_t)r * D + c0);
                    float4 r4; r4.x = g0 * v[0]; r4.y = g0 * v[1]; r4.z = g0 * v[2]; r4.w = g0 * v[3];
                    float4 r5; r5.x = g0 * v[4]; r5.y = g0 * v[5]; r5.z = g0 * v[6]; r5.w = g0 * v[7];
                    pr[0] = r4; pr[1] = r5;
                }
            }
        }
    }
}

// ---------------- launcher ----------------

extern "C" void kernel_launch(void* const* d_in, const int* in_sizes, int n_in,
                              void* d_out, int out_size, void* d_ws, size_t ws_size,
                              hipStream_t stream)
{
    const float* x      = (const float*)d_in[0];
    const float* lin1_w = (const float*)d_in[1];
    const float* lin1_b = (const float*)d_in[2];
    const float* lin2_w = (const float*)d_in[3];
    const float* lin2_b = (const float*)d_in[4];
    const float* gamma  = (const float*)d_in[5];
    const float* p1_w   = (const float*)d_in[6];
    const float* p1_b   = (const float*)d_in[7];
    const float* p2_w   = (const float*)d_in[8];
    const float* p2_b   = (const float*)d_in[9];
    const float* p3_w   = (const float*)d_in[10];
    const float* p3_b   = (const float*)d_in[11];
    const int* src     = (const int*)d_in[12];
    const int* dst     = (const int*)d_in[13];
    const int* pos_src = (const int*)d_in[14];
    const int* pos_dst = (const int*)d_in[15];
    const int* neg_src = (const int*)d_in[16];
    const int* neg_dst = (const int*)d_in[17];

    const int N = in_sizes[0] / D;
    const int E = in_sizes[12];
    const int P = in_sizes[14];

    float* ws = (float*)d_ws;
    size_t fN = (size_t)N * D;
    float* bufB = ws;
    float* bufA = ws + fN;
    float* rep  = ws + 2 * fN;
    char* ip = (char*)(ws + 3 * fN);
    int* cnt_out   = (int*)ip;  ip += (size_t)N * 4;
    int* cnt_in    = (int*)ip;  ip += (size_t)N * 4;
    int* pre       = (int*)ip;  ip += (size_t)N * 4;
    int* row_start = (int*)ip;  ip += (size_t)(N + 1) * 4;
    int* fill_ptr  = (int*)ip;  ip += (size_t)N * 4;
    int* blk_sums  = (int*)ip;  ip += 4096 * 4;
    int* blk_off   = (int*)ip;  ip += 4096 * 4;
    float* dinv_out = (float*)ip; ip += (size_t)N * 4;
    float* dinv_in  = (float*)ip; ip += (size_t)N * 4;
    int* esrc      = (int*)ip;  ip += (size_t)E * 4;
    float* e1;
    if ((size_t)(2 * P) * D <= 2 * fN) {
        e1 = ws;
    } else {
        e1 = (float*)ip; ip += (size_t)(2 * P) * D * 4;
    }

    // ---- degrees + CSR (by dst) ----
    zero_cnt_kernel<<<cdiv(N, 256), 256, 0, stream>>>(cnt_out, cnt_in, N);
    count_kernel<<<cdiv(E, 256), 256, 0, stream>>>(src, dst, cnt_out, cnt_in, E);
    dinv_kernel<<<cdiv(N, 256), 256, 0, stream>>>(cnt_out, cnt_in, dinv_out, dinv_in, N);
    int nblk = cdiv(N, 1024);
    scan_partial<<<nblk, 256, 0, stream>>>(cnt_in, pre, blk_sums, N);
    scan_blk<<<1, 64, 0, stream>>>(blk_sums, blk_off, nblk);
    scan_final<<<cdiv(N, 256), 256, 0, stream>>>(pre, blk_off, row_start, fill_ptr, N, E);
    fill_kernel<<<cdiv(E, 256), 256, 0, stream>>>(src, dst, fill_ptr, esrc, E);

    // ---- node MLP: h1 = relu(x@W1+b1); h0 = h1@W2+b2; rep = gamma0*h0 ----
    gemm128<0><<<cdiv(N, BM), 256, 0, stream>>>(x, lin1_w, lin1_b, bufB, N,
        nullptr, nullptr, nullptr, nullptr, nullptr, nullptr, nullptr);
    gemm128<1><<<cdiv(N, BM), 256, 0, stream>>>(bufB, lin2_w, lin2_b, bufA, N,
        gamma, rep, nullptr, nullptr, nullptr, nullptr, nullptr);

    // ---- 3 propagation layers, rep += gamma[l]*h_l ----
    conv_kernel<<<cdiv(N, 4), 256, 0, stream>>>(bufA, bufB, rep, row_start, esrc,
                                                dinv_out, dinv_in, gamma, 1, N);
    conv_kernel<<<cdiv(N, 4), 256, 0, stream>>>(bufB, bufA, rep, row_start, esrc,
                                                dinv_out, dinv_in, gamma, 2, N);
    conv_kernel<<<cdiv(N, 4), 256, 0, stream>>>(bufA, bufB, rep, row_start, esrc,
                                                dinv_out, dinv_in, gamma, 3, N);

    // ---- predictor ----
    gemm128<2><<<cdiv(P, BM), 256, 0, stream>>>(rep, p1_w, p1_b, e1, P,
        nullptr, nullptr, pos_src, pos_dst, nullptr, nullptr, nullptr);
    gemm128<2><<<cdiv(P, BM), 256, 0, stream>>>(rep, p1_w, p1_b, e1 + (size_t)P * D, P,
        nullptr, nullptr, neg_src, neg_dst, nullptr, nullptr, nullptr);
    gemm128<3><<<cdiv(2 * P, BM), 256, 0, stream>>>(e1, p2_w, p2_b, nullptr, 2 * P,
        nullptr, nullptr, nullptr, nullptr, p3_w, p3_b, (float*)d_out);
}

// Round 6
// 947.414 us; speedup vs baseline: 1.6992x; 1.3874x over previous
//
#include <hip/hip_runtime.h>

#define D 128

typedef _Float16 half8 __attribute__((ext_vector_type(8)));
typedef _Float16 f16x2 __attribute__((ext_vector_type(2)));
typedef float floatx4 __attribute__((ext_vector_type(4)));

static inline int cdiv(int a, int b){ return (a + b - 1) / b; }

// ---------------- degree / CSR build ----------------

__global__ __launch_bounds__(256) void zero_cnt_kernel(int* __restrict__ cnt_out,
                                                       int* __restrict__ cnt_in, int n)
{
    int i = blockIdx.x * 256 + threadIdx.x;
    if (i < n) { cnt_out[i] = 0; cnt_in[i] = 0; }
}

__global__ __launch_bounds__(256) void count_kernel(const int* __restrict__ src,
                                                    const int* __restrict__ dst,
                                                    int* __restrict__ cnt_out,
                                                    int* __restrict__ cnt_in, int E)
{
    int i = blockIdx.x * 256 + threadIdx.x;
    if (i < E) {
        atomicAdd(&cnt_out[src[i]], 1);
        atomicAdd(&cnt_in[dst[i]], 1);
    }
}

__global__ __launch_bounds__(256) void dinv_kernel(const int* __restrict__ cnt_out,
                                                   const int* __restrict__ cnt_in,
                                                   float* __restrict__ dinv_out,
                                                   float* __restrict__ dinv_in, int n)
{
    int i = blockIdx.x * 256 + threadIdx.x;
    if (i < n) {
        dinv_out[i] = rsqrtf(fmaxf((float)cnt_out[i], 1.0f));
        dinv_in[i]  = rsqrtf(fmaxf((float)cnt_in[i],  1.0f));
    }
}

__global__ __launch_bounds__(256) void scan_partial(const int* __restrict__ cnt,
                                                    int* __restrict__ pre,
                                                    int* __restrict__ blk_sums, int n)
{
    __shared__ int lds[256];
    int t = threadIdx.x;
    int base = blockIdx.x * 1024 + t * 4;
    int v0 = 0, v1 = 0, v2 = 0, v3 = 0;
    if (base + 0 < n) v0 = cnt[base + 0];
    if (base + 1 < n) v1 = cnt[base + 1];
    if (base + 2 < n) v2 = cnt[base + 2];
    if (base + 3 < n) v3 = cnt[base + 3];
    int ts = v0 + v1 + v2 + v3;
    lds[t] = ts;
    __syncthreads();
    for (int off = 1; off < 256; off <<= 1) {
        int add = (t >= off) ? lds[t - off] : 0;
        __syncthreads();
        lds[t] += add;
        __syncthreads();
    }
    int excl = lds[t] - ts;
    if (base + 0 < n) pre[base + 0] = excl;
    if (base + 1 < n) pre[base + 1] = excl + v0;
    if (base + 2 < n) pre[base + 2] = excl + v0 + v1;
    if (base + 3 < n) pre[base + 3] = excl + v0 + v1 + v2;
    if (t == 255) blk_sums[blockIdx.x] = lds[255];
}

__global__ void scan_blk(const int* __restrict__ blk_sums, int* __restrict__ blk_off, int nblk)
{
    if (threadIdx.x == 0 && blockIdx.x == 0) {
        int run = 0;
        for (int j = 0; j < nblk; ++j) { blk_off[j] = run; run += blk_sums[j]; }
    }
}

__global__ __launch_bounds__(256) void scan_final(const int* __restrict__ pre,
                                                  const int* __restrict__ blk_off,
                                                  int* __restrict__ row_start,
                                                  int* __restrict__ fill_ptr, int n, int E)
{
    int i = blockIdx.x * 256 + threadIdx.x;
    if (i < n) {
        int v = pre[i] + blk_off[i >> 10];
        row_start[i] = v;
        fill_ptr[i]  = v;
    }
    if (i == 0) row_start[n] = E;
}

__global__ __launch_bounds__(256) void fill_kernel(const int* __restrict__ src,
                                                   const int* __restrict__ dst,
                                                   int* __restrict__ fill_ptr,
                                                   int* __restrict__ esrc, int E)
{
    int i = blockIdx.x * 256 + threadIdx.x;
    if (i < E) {
        int p = atomicAdd(&fill_ptr[dst[i]], 1);
        esrc[p] = src[i];
    }
}

// ---------------- weight transpose + f16 convert: Wt[n][k] = (f16)W[k][n] ----------------
__global__ __launch_bounds__(256) void wt_kernel(const float* __restrict__ W,
                                                 _Float16* __restrict__ Wt)
{
    __shared__ float tile[32][33];
    const int b = blockIdx.x;
    const int tx = b & 3, ty = b >> 2;          // 4x4 tiles of 32x32
    const int t = threadIdx.x;
    const int r = t >> 3, c4 = (t & 7) * 4;
    const float4 v = *(const float4*)&W[(size_t)(ty * 32 + r) * D + tx * 32 + c4];
    tile[r][c4 + 0] = v.x; tile[r][c4 + 1] = v.y;
    tile[r][c4 + 2] = v.z; tile[r][c4 + 3] = v.w;
    __syncthreads();
    // out row n = tx*32 + r ; k = ty*32 + c4 + j ; value = W[k][n] = tile[c4+j][r]
    _Float16* dst = Wt + (size_t)(tx * 32 + r) * D + ty * 32 + c4;
    dst[0] = (_Float16)tile[c4 + 0][r];
    dst[1] = (_Float16)tile[c4 + 1][r];
    dst[2] = (_Float16)tile[c4 + 2][r];
    dst[3] = (_Float16)tile[c4 + 3][r];
}

// ---------------- graph conv (f16 h, f32 rep) ----------------
__global__ __launch_bounds__(256, 4) void conv_f16(const _Float16* __restrict__ hin,
                                                   _Float16* __restrict__ hout,
                                                   float* __restrict__ rep,
                                                   const int* __restrict__ row_start,
                                                   const int* __restrict__ esrc,
                                                   const float* __restrict__ dinv_out,
                                                   const float* __restrict__ dinv_in,
                                                   const float* __restrict__ gamma,
                                                   int lidx, int n)
{
    int wid  = (blockIdx.x * 256 + threadIdx.x) >> 6;
    int lane = threadIdx.x & 63;
    if (wid >= n) return;
    int rs = row_start[wid];
    int re = row_start[wid + 1];
    const f16x2* hb = (const f16x2*)hin;
    float ax = 0.f, ay = 0.f;
    for (int i = rs; i < re; ++i) {
        int s = esrc[i];
        float sc = dinv_out[s];
        f16x2 v = hb[(size_t)s * 64 + lane];
        ax += (float)v[0] * sc;
        ay += (float)v[1] * sc;
    }
    float di = dinv_in[wid];
    float g  = gamma[lidx];
    float hx = ax * di, hy = ay * di;
    f16x2 o; o[0] = (_Float16)hx; o[1] = (_Float16)hy;
    ((f16x2*)hout)[(size_t)wid * 64 + lane] = o;
    float2* rp = (float2*)rep + (size_t)wid * 64 + lane;
    float2 rv = *rp;
    rv.x += g * hx;
    rv.y += g * hy;
    *rp = rv;
}

// ---------------- MFMA f16 GEMM: out[R x 128] = op(A) @ W + b ----------------
// block 256 = 4 waves; tile 128 rows x 128 cols; whole K=128 staged once.
// LDS 16B-chunk swizzle: chunk c at row r stored at c^(r&15)  (kills the
// 256B-row-stride same-bank conflict on ds_read_b128, guide §6 G4).
// MODE 0: A = Xf[row]                  -> outh = relu
// MODE 1: A = Xh[row] (f16)            -> outh = raw ; rep = gamma[0]*val
// MODE 2: A = Xf[ia[row]]*Xf[ib[row]]  -> outh = relu
// MODE 3: A = Xh[row] (f16), e2=relu() -> outsc[row] = dot(e2,w3)+b3
__device__ __forceinline__ int lds_off(int r, int chunk)
{
    return r * D + ((chunk ^ (r & 15)) << 3);
}

template<int MODE>
__global__ __launch_bounds__(256, 2) void gemm_mfma(const float* __restrict__ Xf,
                                                    const _Float16* __restrict__ Xh,
                                                    const _Float16* __restrict__ Wt,
                                                    const float* __restrict__ B, int R,
                                                    _Float16* __restrict__ outh,
                                                    float* __restrict__ rep,
                                                    const float* __restrict__ gamma,
                                                    const int* __restrict__ ia,
                                                    const int* __restrict__ ib,
                                                    const float* __restrict__ w3,
                                                    const float* __restrict__ b3,
                                                    float* __restrict__ outsc)
{
    __shared__ _Float16 Als[D * D];
    __shared__ _Float16 Wls[D * D];
    const int t = threadIdx.x;
    const int rowbase = blockIdx.x * D;

    #pragma unroll
    for (int it = 0; it < 8; ++it) {
        const int r = it * 16 + (t >> 4);
        const int c = t & 15;
        // stage Wt row r (f16, coalesced 16B/lane)
        *(half8*)&Wls[lds_off(r, c)] = *(const half8*)(Wt + (size_t)r * D + c * 8);
        // stage A row (clamped at edge; outputs gated later)
        int g = rowbase + r; if (g > R - 1) g = R - 1;
        half8 hv;
        if (MODE == 0) {
            const float4* ap = (const float4*)(Xf + (size_t)g * D + c * 8);
            float4 a0 = ap[0], a1 = ap[1];
            hv[0] = (_Float16)a0.x; hv[1] = (_Float16)a0.y;
            hv[2] = (_Float16)a0.z; hv[3] = (_Float16)a0.w;
            hv[4] = (_Float16)a1.x; hv[5] = (_Float16)a1.y;
            hv[6] = (_Float16)a1.z; hv[7] = (_Float16)a1.w;
        } else if (MODE == 2) {
            const float4* pa = (const float4*)(Xf + (size_t)ia[g] * D + c * 8);
            const float4* pb = (const float4*)(Xf + (size_t)ib[g] * D + c * 8);
            float4 a0 = pa[0], a1 = pa[1], b0 = pb[0], b1 = pb[1];
            hv[0] = (_Float16)(a0.x * b0.x); hv[1] = (_Float16)(a0.y * b0.y);
            hv[2] = (_Float16)(a0.z * b0.z); hv[3] = (_Float16)(a0.w * b0.w);
            hv[4] = (_Float16)(a1.x * b1.x); hv[5] = (_Float16)(a1.y * b1.y);
            hv[6] = (_Float16)(a1.z * b1.z); hv[7] = (_Float16)(a1.w * b1.w);
        } else {
            hv = *(const half8*)(Xh + (size_t)g * D + c * 8);
        }
        *(half8*)&Als[lds_off(r, c)] = hv;
    }
    __syncthreads();

    const int wid = t >> 6;          // wave -> rows [wid*32, wid*32+32)
    const int l   = t & 63;
    const int lr  = l & 15;
    const int lq  = l >> 4;

    floatx4 acc[2][8];
    #pragma unroll
    for (int m = 0; m < 2; ++m)
        #pragma unroll
        for (int n = 0; n < 8; ++n) {
            acc[m][n][0] = 0.f; acc[m][n][1] = 0.f;
            acc[m][n][2] = 0.f; acc[m][n][3] = 0.f;
        }

    #pragma unroll
    for (int kk = 0; kk < 4; ++kk) {
        const int cc = kk * 4 + lq;
        half8 af[2], bf[8];
        #pragma unroll
        for (int m = 0; m < 2; ++m) {
            const int r = wid * 32 + m * 16 + lr;
            af[m] = *(half8*)&Als[lds_off(r, cc)];
        }
        #pragma unroll
        for (int n = 0; n < 8; ++n) {
            const int r = n * 16 + lr;
            bf[n] = *(half8*)&Wls[lds_off(r, cc)];
        }
        #pragma unroll
        for (int m = 0; m < 2; ++m)
            #pragma unroll
            for (int n = 0; n < 8; ++n)
                acc[m][n] = __builtin_amdgcn_mfma_f32_16x16x32_f16(af[m], bf[n], acc[m][n], 0, 0, 0);
    }

    // C/D layout (guide §3, m89-verified): col = lane&15, row = (lane>>4)*4 + reg
    if (MODE == 3) {
        float bv[8], wv[8];
        #pragma unroll
        for (int n = 0; n < 8; ++n) { bv[n] = B[n * 16 + lr]; wv[n] = w3[n * 16 + lr]; }
        const float bb = b3[0];
        #pragma unroll
        for (int m = 0; m < 2; ++m) {
            #pragma unroll
            for (int q = 0; q < 4; ++q) {
                float s = 0.f;
                #pragma unroll
                for (int n = 0; n < 8; ++n)
                    s += fmaxf(acc[m][n][q] + bv[n], 0.f) * wv[n];
                s += __shfl_xor(s, 1); s += __shfl_xor(s, 2);
                s += __shfl_xor(s, 4); s += __shfl_xor(s, 8);
                const int r = rowbase + wid * 32 + m * 16 + lq * 4 + q;
                if (lr == 0 && r < R) outsc[r] = s + bb;
            }
        }
    } else {
        float bv[8];
        #pragma unroll
        for (int n = 0; n < 8; ++n) bv[n] = B[n * 16 + lr];
        const float g0 = (MODE == 1) ? gamma[0] : 0.f;
        #pragma unroll
        for (int m = 0; m < 2; ++m) {
            #pragma unroll
            for (int q = 0; q < 4; ++q) {
                const int r = rowbase + wid * 32 + m * 16 + lq * 4 + q;
                if (r < R) {
                    #pragma unroll
                    for (int n = 0; n < 8; ++n) {
                        float v = acc[m][n][q] + bv[n];
                        if (MODE != 1) v = fmaxf(v, 0.f);
                        outh[(size_t)r * D + n * 16 + lr] = (_Float16)v;
                        if (MODE == 1) rep[(size_t)r * D + n * 16 + lr] = g0 * v;
                    }
                }
            }
        }
    }
}

// ---------------- launcher ----------------

extern "C" void kernel_launch(void* const* d_in, const int* in_sizes, int n_in,
                              void* d_out, int out_size, void* d_ws, size_t ws_size,
                              hipStream_t stream)
{
    const float* x      = (const float*)d_in[0];
    const float* lin1_w = (const float*)d_in[1];
    const float* lin1_b = (const float*)d_in[2];
    const float* lin2_w = (const float*)d_in[3];
    const float* lin2_b = (const float*)d_in[4];
    const float* gamma  = (const float*)d_in[5];
    const float* p1_w   = (const float*)d_in[6];
    const float* p1_b   = (const float*)d_in[7];
    const float* p2_w   = (const float*)d_in[8];
    const float* p2_b   = (const float*)d_in[9];
    const float* p3_w   = (const float*)d_in[10];
    const float* p3_b   = (const float*)d_in[11];
    const int* src     = (const int*)d_in[12];
    const int* dst     = (const int*)d_in[13];
    const int* pos_src = (const int*)d_in[14];
    const int* pos_dst = (const int*)d_in[15];
    const int* neg_src = (const int*)d_in[16];
    const int* neg_dst = (const int*)d_in[17];

    const int N = in_sizes[0] / D;
    const int E = in_sizes[12];
    const int P = in_sizes[14];

    char* base = (char*)d_ws;
    _Float16* bufB = (_Float16*)base;                    // h1 (f16)
    _Float16* bufA = bufB + (size_t)N * D;               // h0 / conv pong (f16)
    float*    rep  = (float*)(bufA + (size_t)N * D);     // f32 accumulation
    _Float16* wt1  = (_Float16*)(rep + (size_t)N * D);
    _Float16* wt2  = wt1 + D * D;
    _Float16* wtp1 = wt2 + D * D;
    _Float16* wtp2 = wtp1 + D * D;
    char* ip = (char*)(wtp2 + D * D);
    int* cnt_out   = (int*)ip;  ip += (size_t)N * 4;
    int* cnt_in    = (int*)ip;  ip += (size_t)N * 4;
    int* pre       = (int*)ip;  ip += (size_t)N * 4;
    int* row_start = (int*)ip;  ip += (size_t)(N + 1) * 4;
    int* fill_ptr  = (int*)ip;  ip += (size_t)N * 4;
    int* blk_sums  = (int*)ip;  ip += 4096 * 4;
    int* blk_off   = (int*)ip;  ip += 4096 * 4;
    float* dinv_out = (float*)ip; ip += (size_t)N * 4;
    float* dinv_in  = (float*)ip; ip += (size_t)N * 4;
    int* esrc      = (int*)ip;  ip += (size_t)E * 4;
    // e1 [2P x D] f16 overlaps bufB+bufA (dead after conv3) when it fits
    _Float16* e1;
    if ((size_t)(2 * P) <= 2 * (size_t)N) {
        e1 = (_Float16*)base;
    } else {
        e1 = (_Float16*)ip; ip += (size_t)(2 * P) * D * 2;
    }

    // ---- degrees + CSR (by dst) ----
    zero_cnt_kernel<<<cdiv(N, 256), 256, 0, stream>>>(cnt_out, cnt_in, N);
    count_kernel<<<cdiv(E, 256), 256, 0, stream>>>(src, dst, cnt_out, cnt_in, E);
    dinv_kernel<<<cdiv(N, 256), 256, 0, stream>>>(cnt_out, cnt_in, dinv_out, dinv_in, N);
    int nblk = cdiv(N, 1024);
    scan_partial<<<nblk, 256, 0, stream>>>(cnt_in, pre, blk_sums, N);
    scan_blk<<<1, 64, 0, stream>>>(blk_sums, blk_off, nblk);
    scan_final<<<cdiv(N, 256), 256, 0, stream>>>(pre, blk_off, row_start, fill_ptr, N, E);
    fill_kernel<<<cdiv(E, 256), 256, 0, stream>>>(src, dst, fill_ptr, esrc, E);

    // ---- weight transpose + f16 ----
    wt_kernel<<<16, 256, 0, stream>>>(lin1_w, wt1);
    wt_kernel<<<16, 256, 0, stream>>>(lin2_w, wt2);
    wt_kernel<<<16, 256, 0, stream>>>(p1_w, wtp1);
    wt_kernel<<<16, 256, 0, stream>>>(p2_w, wtp2);

    // ---- node MLP ----
    gemm_mfma<0><<<cdiv(N, 128), 256, 0, stream>>>(x, nullptr, wt1, lin1_b, N,
        bufB, nullptr, nullptr, nullptr, nullptr, nullptr, nullptr, nullptr);
    gemm_mfma<1><<<cdiv(N, 128), 256, 0, stream>>>(nullptr, bufB, wt2, lin2_b, N,
        bufA, rep, gamma, nullptr, nullptr, nullptr, nullptr, nullptr);

    // ---- 3 propagation layers ----
    conv_f16<<<cdiv(N, 4), 256, 0, stream>>>(bufA, bufB, rep, row_start, esrc,
                                             dinv_out, dinv_in, gamma, 1, N);
    conv_f16<<<cdiv(N, 4), 256, 0, stream>>>(bufB, bufA, rep, row_start, esrc,
                                             dinv_out, dinv_in, gamma, 2, N);
    conv_f16<<<cdiv(N, 4), 256, 0, stream>>>(bufA, bufB, rep, row_start, esrc,
                                             dinv_out, dinv_in, gamma, 3, N);

    // ---- predictor ----
    gemm_mfma<2><<<cdiv(P, 128), 256, 0, stream>>>(rep, nullptr, wtp1, p1_b, P,
        e1, nullptr, nullptr, pos_src, pos_dst, nullptr, nullptr, nullptr);
    gemm_mfma<2><<<cdiv(P, 128), 256, 0, stream>>>(rep, nullptr, wtp1, p1_b, P,
        e1 + (size_t)P * D, nullptr, nullptr, neg_src, neg_dst, nullptr, nullptr, nullptr);
    gemm_mfma<3><<<cdiv(2 * P, 128), 256, 0, stream>>>(nullptr, e1, wtp2, p2_b, 2 * P,
        nullptr, nullptr, nullptr, nullptr, nullptr, p3_w, p3_b, (float*)d_out);
}

// Round 11
// 697.847 us; speedup vs baseline: 2.3069x; 1.3576x over previous
//
#include <hip/hip_runtime.h>

#define D 128

typedef _Float16 half8 __attribute__((ext_vector_type(8)));
typedef _Float16 f16x2 __attribute__((ext_vector_type(2)));
typedef float floatx4 __attribute__((ext_vector_type(4)));

static inline int cdiv(int a, int b){ return (a + b - 1) / b; }

// ---------------- degree / CSR build ----------------

__global__ __launch_bounds__(256) void zero_cnt_kernel(int* __restrict__ cnt_out,
                                                       int* __restrict__ cnt_in, int n)
{
    int i = blockIdx.x * 256 + threadIdx.x;
    if (i < n) { cnt_out[i] = 0; cnt_in[i] = 0; }
}

__global__ __launch_bounds__(256) void count_kernel(const int* __restrict__ src,
                                                    const int* __restrict__ dst,
                                                    int* __restrict__ cnt_out,
                                                    int* __restrict__ cnt_in, int E)
{
    int i = blockIdx.x * 256 + threadIdx.x;
    if (i < E) {
        atomicAdd(&cnt_out[src[i]], 1);
        atomicAdd(&cnt_in[dst[i]], 1);
    }
}

__global__ __launch_bounds__(256) void dinv_kernel(const int* __restrict__ cnt_out,
                                                   const int* __restrict__ cnt_in,
                                                   float* __restrict__ dinv_out,
                                                   float* __restrict__ dinv_in, int n)
{
    int i = blockIdx.x * 256 + threadIdx.x;
    if (i < n) {
        dinv_out[i] = rsqrtf(fmaxf((float)cnt_out[i], 1.0f));
        dinv_in[i]  = rsqrtf(fmaxf((float)cnt_in[i],  1.0f));
    }
}

__global__ __launch_bounds__(256) void scan_partial(const int* __restrict__ cnt,
                                                    int* __restrict__ pre,
                                                    int* __restrict__ blk_sums, int n)
{
    __shared__ int lds[256];
    int t = threadIdx.x;
    int base = blockIdx.x * 1024 + t * 4;
    int v0 = 0, v1 = 0, v2 = 0, v3 = 0;
    if (base + 0 < n) v0 = cnt[base + 0];
    if (base + 1 < n) v1 = cnt[base + 1];
    if (base + 2 < n) v2 = cnt[base + 2];
    if (base + 3 < n) v3 = cnt[base + 3];
    int ts = v0 + v1 + v2 + v3;
    lds[t] = ts;
    __syncthreads();
    for (int off = 1; off < 256; off <<= 1) {
        int add = (t >= off) ? lds[t - off] : 0;
        __syncthreads();
        lds[t] += add;
        __syncthreads();
    }
    int excl = lds[t] - ts;
    if (base + 0 < n) pre[base + 0] = excl;
    if (base + 1 < n) pre[base + 1] = excl + v0;
    if (base + 2 < n) pre[base + 2] = excl + v0 + v1;
    if (base + 3 < n) pre[base + 3] = excl + v0 + v1 + v2;
    if (t == 255) blk_sums[blockIdx.x] = lds[255];
}

__global__ void scan_blk(const int* __restrict__ blk_sums, int* __restrict__ blk_off, int nblk)
{
    if (threadIdx.x == 0 && blockIdx.x == 0) {
        int run = 0;
        for (int j = 0; j < nblk; ++j) { blk_off[j] = run; run += blk_sums[j]; }
    }
}

__global__ __launch_bounds__(256) void scan_final(const int* __restrict__ pre,
                                                  const int* __restrict__ blk_off,
                                                  int* __restrict__ row_start,
                                                  int* __restrict__ fill_ptr, int n, int E)
{
    int i = blockIdx.x * 256 + threadIdx.x;
    if (i < n) {
        int v = pre[i] + blk_off[i >> 10];
        row_start[i] = v;
        fill_ptr[i]  = v;
    }
    if (i == 0) row_start[n] = E;
}

__global__ __launch_bounds__(256) void fill_kernel(const int* __restrict__ src,
                                                   const int* __restrict__ dst,
                                                   int* __restrict__ fill_ptr,
                                                   int* __restrict__ esrc, int E)
{
    int i = blockIdx.x * 256 + threadIdx.x;
    if (i < E) {
        int p = atomicAdd(&fill_ptr[dst[i]], 1);
        esrc[p] = src[i];
    }
}

// ---------------- weight transpose + f16 convert: Wt[n][k] = (f16)W[k][n] ----------------
__global__ __launch_bounds__(256) void wt_kernel(const float* __restrict__ W,
                                                 _Float16* __restrict__ Wt)
{
    __shared__ float tile[32][33];
    const int b = blockIdx.x;
    const int tx = b & 3, ty = b >> 2;          // 4x4 tiles of 32x32
    const int t = threadIdx.x;
    const int r = t >> 3, c4 = (t & 7) * 4;
    const float4 v = *(const float4*)&W[(size_t)(ty * 32 + r) * D + tx * 32 + c4];
    tile[r][c4 + 0] = v.x; tile[r][c4 + 1] = v.y;
    tile[r][c4 + 2] = v.z; tile[r][c4 + 3] = v.w;
    __syncthreads();
    _Float16* dst = Wt + (size_t)(tx * 32 + r) * D + ty * 32 + c4;
    dst[0] = (_Float16)tile[c4 + 0][r];
    dst[1] = (_Float16)tile[c4 + 1][r];
    dst[2] = (_Float16)tile[c4 + 2][r];
    dst[3] = (_Float16)tile[c4 + 3][r];
}

// ---------------- graph conv (f16 h, f32 rep) ----------------
// 16 lanes per node (each lane: 8 dims, half8=16B loads); 4 nodes per wave;
// edge loop unrolled x2 -> up to 8 independent gathers in flight per wave
// (round-6 counters: 1-gather/wave serial chain was latency-bound at 162us).
__global__ __launch_bounds__(256, 4) void conv_f16(const _Float16* __restrict__ hin,
                                                   _Float16* __restrict__ hout,
                                                   float* __restrict__ rep,
                                                   const int* __restrict__ row_start,
                                                   const int* __restrict__ esrc,
                                                   const float* __restrict__ dinv_out,
                                                   const float* __restrict__ dinv_in,
                                                   const float* __restrict__ gamma,
                                                   int lidx, int n)
{
    const int node = (blockIdx.x * 256 + threadIdx.x) >> 4;   // 16 nodes / block
    const int sub  = threadIdx.x & 15;                        // dims [sub*8, sub*8+8)
    if (node >= n) return;
    const int rs = row_start[node];
    const int re = row_start[node + 1];
    const half8* hb = (const half8*)hin;

    float acc[8] = {0.f, 0.f, 0.f, 0.f, 0.f, 0.f, 0.f, 0.f};
    int i = rs;
    for (; i + 1 < re; i += 2) {
        const int s0 = esrc[i];
        const int s1 = esrc[i + 1];
        const float c0 = dinv_out[s0];
        const float c1 = dinv_out[s1];
        const half8 v0 = hb[(size_t)s0 * 16 + sub];
        const half8 v1 = hb[(size_t)s1 * 16 + sub];
        #pragma unroll
        for (int j = 0; j < 8; ++j)
            acc[j] += (float)v0[j] * c0 + (float)v1[j] * c1;
    }
    if (i < re) {
        const int s0 = esrc[i];
        const float c0 = dinv_out[s0];
        const half8 v0 = hb[(size_t)s0 * 16 + sub];
        #pragma unroll
        for (int j = 0; j < 8; ++j)
            acc[j] += (float)v0[j] * c0;
    }

    const float di = dinv_in[node];
    const float g  = gamma[lidx];
    half8 o;
    #pragma unroll
    for (int j = 0; j < 8; ++j) {
        acc[j] *= di;
        o[j] = (_Float16)acc[j];
    }
    ((half8*)hout)[(size_t)node * 16 + sub] = o;

    floatx4* rp = (floatx4*)(rep + (size_t)node * D + sub * 8);
    floatx4 r0 = rp[0], r1 = rp[1];
    r0[0] += g * acc[0]; r0[1] += g * acc[1]; r0[2] += g * acc[2]; r0[3] += g * acc[3];
    r1[0] += g * acc[4]; r1[1] += g * acc[5]; r1[2] += g * acc[6]; r1[3] += g * acc[7];
    rp[0] = r0; rp[1] = r1;
}

// ---------------- MFMA f16 GEMM: out[R x 128] = op(A) @ W + b ----------------
__device__ __forceinline__ int lds_off(int r, int chunk)
{
    return r * D + ((chunk ^ (r & 15)) << 3);
}

template<int MODE>
__global__ __launch_bounds__(256, 2) void gemm_mfma(const float* __restrict__ Xf,
                                                    const _Float16* __restrict__ Xh,
                                                    const _Float16* __restrict__ Wt,
                                                    const float* __restrict__ B, int R,
                                                    _Float16* __restrict__ outh,
                                                    float* __restrict__ rep,
                                                    const float* __restrict__ gamma,
                                                    const int* __restrict__ ia,
                                                    const int* __restrict__ ib,
                                                    const float* __restrict__ w3,
                                                    const float* __restrict__ b3,
                                                    float* __restrict__ outsc)
{
    __shared__ _Float16 Als[D * D];
    __shared__ _Float16 Wls[D * D];
    const int t = threadIdx.x;
    const int rowbase = blockIdx.x * D;

    #pragma unroll
    for (int it = 0; it < 8; ++it) {
        const int r = it * 16 + (t >> 4);
        const int c = t & 15;
        *(half8*)&Wls[lds_off(r, c)] = *(const half8*)(Wt + (size_t)r * D + c * 8);
        int g = rowbase + r; if (g > R - 1) g = R - 1;
        half8 hv;
        if (MODE == 0) {
            const float4* ap = (const float4*)(Xf + (size_t)g * D + c * 8);
            float4 a0 = ap[0], a1 = ap[1];
            hv[0] = (_Float16)a0.x; hv[1] = (_Float16)a0.y;
            hv[2] = (_Float16)a0.z; hv[3] = (_Float16)a0.w;
            hv[4] = (_Float16)a1.x; hv[5] = (_Float16)a1.y;
            hv[6] = (_Float16)a1.z; hv[7] = (_Float16)a1.w;
        } else if (MODE == 2) {
            const float4* pa = (const float4*)(Xf + (size_t)ia[g] * D + c * 8);
            const float4* pb = (const float4*)(Xf + (size_t)ib[g] * D + c * 8);
            float4 a0 = pa[0], a1 = pa[1], b0 = pb[0], b1 = pb[1];
            hv[0] = (_Float16)(a0.x * b0.x); hv[1] = (_Float16)(a0.y * b0.y);
            hv[2] = (_Float16)(a0.z * b0.z); hv[3] = (_Float16)(a0.w * b0.w);
            hv[4] = (_Float16)(a1.x * b1.x); hv[5] = (_Float16)(a1.y * b1.y);
            hv[6] = (_Float16)(a1.z * b1.z); hv[7] = (_Float16)(a1.w * b1.w);
        } else {
            hv = *(const half8*)(Xh + (size_t)g * D + c * 8);
        }
        *(half8*)&Als[lds_off(r, c)] = hv;
    }
    __syncthreads();

    const int wid = t >> 6;
    const int l   = t & 63;
    const int lr  = l & 15;
    const int lq  = l >> 4;

    floatx4 acc[2][8];
    #pragma unroll
    for (int m = 0; m < 2; ++m)
        #pragma unroll
        for (int n = 0; n < 8; ++n) {
            acc[m][n][0] = 0.f; acc[m][n][1] = 0.f;
            acc[m][n][2] = 0.f; acc[m][n][3] = 0.f;
        }

    #pragma unroll
    for (int kk = 0; kk < 4; ++kk) {
        const int cc = kk * 4 + lq;
        half8 af[2], bf[8];
        #pragma unroll
        for (int m = 0; m < 2; ++m) {
            const int r = wid * 32 + m * 16 + lr;
            af[m] = *(half8*)&Als[lds_off(r, cc)];
        }
        #pragma unroll
        for (int n = 0; n < 8; ++n) {
            const int r = n * 16 + lr;
            bf[n] = *(half8*)&Wls[lds_off(r, cc)];
        }
        #pragma unroll
        for (int m = 0; m < 2; ++m)
            #pragma unroll
            for (int n = 0; n < 8; ++n)
                acc[m][n] = __builtin_amdgcn_mfma_f32_16x16x32_f16(af[m], bf[n], acc[m][n], 0, 0, 0);
    }

    // C/D layout: col = lane&15, row = (lane>>4)*4 + reg
    if (MODE == 3) {
        float bv[8], wv[8];
        #pragma unroll
        for (int n = 0; n < 8; ++n) { bv[n] = B[n * 16 + lr]; wv[n] = w3[n * 16 + lr]; }
        const float bb = b3[0];
        #pragma unroll
        for (int m = 0; m < 2; ++m) {
            #pragma unroll
            for (int q = 0; q < 4; ++q) {
                float s = 0.f;
                #pragma unroll
                for (int n = 0; n < 8; ++n)
                    s += fmaxf(acc[m][n][q] + bv[n], 0.f) * wv[n];
                s += __shfl_xor(s, 1); s += __shfl_xor(s, 2);
                s += __shfl_xor(s, 4); s += __shfl_xor(s, 8);
                const int r = rowbase + wid * 32 + m * 16 + lq * 4 + q;
                if (lr == 0 && r < R) outsc[r] = s + bb;
            }
        }
    } else {
        float bv[8];
        #pragma unroll
        for (int n = 0; n < 8; ++n) bv[n] = B[n * 16 + lr];
        const float g0 = (MODE == 1) ? gamma[0] : 0.f;
        #pragma unroll
        for (int m = 0; m < 2; ++m) {
            #pragma unroll
            for (int q = 0; q < 4; ++q) {
                const int r = rowbase + wid * 32 + m * 16 + lq * 4 + q;
                if (r < R) {
                    #pragma unroll
                    for (int n = 0; n < 8; ++n) {
                        float v = acc[m][n][q] + bv[n];
                        if (MODE != 1) v = fmaxf(v, 0.f);
                        outh[(size_t)r * D + n * 16 + lr] = (_Float16)v;
                        if (MODE == 1) rep[(size_t)r * D + n * 16 + lr] = g0 * v;
                    }
                }
            }
        }
    }
}

// ---------------- launcher ----------------

extern "C" void kernel_launch(void* const* d_in, const int* in_sizes, int n_in,
                              void* d_out, int out_size, void* d_ws, size_t ws_size,
                              hipStream_t stream)
{
    const float* x      = (const float*)d_in[0];
    const float* lin1_w = (const float*)d_in[1];
    const float* lin1_b = (const float*)d_in[2];
    const float* lin2_w = (const float*)d_in[3];
    const float* lin2_b = (const float*)d_in[4];
    const float* gamma  = (const float*)d_in[5];
    const float* p1_w   = (const float*)d_in[6];
    const float* p1_b   = (const float*)d_in[7];
    const float* p2_w   = (const float*)d_in[8];
    const float* p2_b   = (const float*)d_in[9];
    const float* p3_w   = (const float*)d_in[10];
    const float* p3_b   = (const float*)d_in[11];
    const int* src     = (const int*)d_in[12];
    const int* dst     = (const int*)d_in[13];
    const int* pos_src = (const int*)d_in[14];
    const int* pos_dst = (const int*)d_in[15];
    const int* neg_src = (const int*)d_in[16];
    const int* neg_dst = (const int*)d_in[17];

    const int N = in_sizes[0] / D;
    const int E = in_sizes[12];
    const int P = in_sizes[14];

    char* base = (char*)d_ws;
    _Float16* bufB = (_Float16*)base;                    // h1 (f16)
    _Float16* bufA = bufB + (size_t)N * D;               // h0 / conv pong (f16)
    float*    rep  = (float*)(bufA + (size_t)N * D);     // f32 accumulation
    _Float16* wt1  = (_Float16*)(rep + (size_t)N * D);
    _Float16* wt2  = wt1 + D * D;
    _Float16* wtp1 = wt2 + D * D;
    _Float16* wtp2 = wtp1 + D * D;
    char* ip = (char*)(wtp2 + D * D);
    int* cnt_out   = (int*)ip;  ip += (size_t)N * 4;
    int* cnt_in    = (int*)ip;  ip += (size_t)N * 4;
    int* pre       = (int*)ip;  ip += (size_t)N * 4;
    int* row_start = (int*)ip;  ip += (size_t)(N + 1) * 4;
    int* fill_ptr  = (int*)ip;  ip += (size_t)N * 4;
    int* blk_sums  = (int*)ip;  ip += 4096 * 4;
    int* blk_off   = (int*)ip;  ip += 4096 * 4;
    float* dinv_out = (float*)ip; ip += (size_t)N * 4;
    float* dinv_in  = (float*)ip; ip += (size_t)N * 4;
    int* esrc      = (int*)ip;  ip += (size_t)E * 4;
    _Float16* e1;
    if ((size_t)(2 * P) <= 2 * (size_t)N) {
        e1 = (_Float16*)base;
    } else {
        e1 = (_Float16*)ip; ip += (size_t)(2 * P) * D * 2;
    }

    // ---- degrees + CSR (by dst) ----
    zero_cnt_kernel<<<cdiv(N, 256), 256, 0, stream>>>(cnt_out, cnt_in, N);
    count_kernel<<<cdiv(E, 256), 256, 0, stream>>>(src, dst, cnt_out, cnt_in, E);
    dinv_kernel<<<cdiv(N, 256), 256, 0, stream>>>(cnt_out, cnt_in, dinv_out, dinv_in, N);
    int nblk = cdiv(N, 1024);
    scan_partial<<<nblk, 256, 0, stream>>>(cnt_in, pre, blk_sums, N);
    scan_blk<<<1, 64, 0, stream>>>(blk_sums, blk_off, nblk);
    scan_final<<<cdiv(N, 256), 256, 0, stream>>>(pre, blk_off, row_start, fill_ptr, N, E);
    fill_kernel<<<cdiv(E, 256), 256, 0, stream>>>(src, dst, fill_ptr, esrc, E);

    // ---- weight transpose + f16 ----
    wt_kernel<<<16, 256, 0, stream>>>(lin1_w, wt1);
    wt_kernel<<<16, 256, 0, stream>>>(lin2_w, wt2);
    wt_kernel<<<16, 256, 0, stream>>>(p1_w, wtp1);
    wt_kernel<<<16, 256, 0, stream>>>(p2_w, wtp2);

    // ---- node MLP ----
    gemm_mfma<0><<<cdiv(N, 128), 256, 0, stream>>>(x, nullptr, wt1, lin1_b, N,
        bufB, nullptr, nullptr, nullptr, nullptr, nullptr, nullptr, nullptr);
    gemm_mfma<1><<<cdiv(N, 128), 256, 0, stream>>>(nullptr, bufB, wt2, lin2_b, N,
        bufA, rep, gamma, nullptr, nullptr, nullptr, nullptr, nullptr);

    // ---- 3 propagation layers ----
    conv_f16<<<cdiv(N * 16, 256), 256, 0, stream>>>(bufA, bufB, rep, row_start, esrc,
                                                    dinv_out, dinv_in, gamma, 1, N);
    conv_f16<<<cdiv(N * 16, 256), 256, 0, stream>>>(bufB, bufA, rep, row_start, esrc,
                                                    dinv_out, dinv_in, gamma, 2, N);
    conv_f16<<<cdiv(N * 16, 256), 256, 0, stream>>>(bufA, bufB, rep, row_start, esrc,
                                                    dinv_out, dinv_in, gamma, 3, N);

    // ---- predictor ----
    gemm_mfma<2><<<cdiv(P, 128), 256, 0, stream>>>(rep, nullptr, wtp1, p1_b, P,
        e1, nullptr, nullptr, pos_src, pos_dst, nullptr, nullptr, nullptr);
    gemm_mfma<2><<<cdiv(P, 128), 256, 0, stream>>>(rep, nullptr, wtp1, p1_b, P,
        e1 + (size_t)P * D, nullptr, nullptr, neg_src, neg_dst, nullptr, nullptr, nullptr);
    gemm_mfma<3><<<cdiv(2 * P, 128), 256, 0, stream>>>(nullptr, e1, wtp2, p2_b, 2 * P,
        nullptr, nullptr, nullptr, nullptr, nullptr, p3_w, p3_b, (float*)d_out);
}

// Round 13
// 642.183 us; speedup vs baseline: 2.5068x; 1.0867x over previous
//
#include <hip/hip_runtime.h>

#define D 128
#define HBINS 16384      // 2^14 bins = 64 KB LDS histogram per block
#define HCHUNKS 32       // edge chunks per node-range

typedef _Float16 half8 __attribute__((ext_vector_type(8)));
typedef float floatx4 __attribute__((ext_vector_type(4)));

__host__ __device__ static inline int cdiv(int a, int b){ return (a + b - 1) / b; }

// ---------------- no-atomic degree histograms ----------------
// grid = NR*HCHUNKS blocks; block (r,c): LDS-histogram values in range r from
// edge chunk c, flush partial coalesced. Replaces 3.2M global atomic RMWs
// (count_kernel, 124us, 100MB fabric RMW @0.85TB/s) with coalesced streams.
__global__ __launch_bounds__(256) void hist_kernel(const int* __restrict__ vals, int E,
                                                   int* __restrict__ part)
{
    __shared__ int h[HBINS];
    const int r = blockIdx.x / HCHUNKS;
    const int c = blockIdx.x % HCHUNKS;
    for (int i = threadIdx.x; i < HBINS; i += 256) h[i] = 0;
    __syncthreads();

    int elen = cdiv(E, HCHUNKS);
    elen = (elen + 3) & ~3;
    const int lo = c * elen;
    const int hi = min(E, lo + elen);
    if (lo < hi) {
        const int nfull = (hi - lo) >> 2;
        const int4* v4 = (const int4*)(vals + lo);
        for (int i = threadIdx.x; i < nfull; i += 256) {
            const int4 v = v4[i];
            if ((v.x >> 14) == r) atomicAdd(&h[v.x & (HBINS - 1)], 1);
            if ((v.y >> 14) == r) atomicAdd(&h[v.y & (HBINS - 1)], 1);
            if ((v.z >> 14) == r) atomicAdd(&h[v.z & (HBINS - 1)], 1);
            if ((v.w >> 14) == r) atomicAdd(&h[v.w & (HBINS - 1)], 1);
        }
        for (int i = lo + (nfull << 2) + threadIdx.x; i < hi; i += 256) {
            const int v = vals[i];
            if ((v >> 14) == r) atomicAdd(&h[v & (HBINS - 1)], 1);
        }
    }
    __syncthreads();
    int* dstp = part + (size_t)blockIdx.x * HBINS;
    for (int i = threadIdx.x; i < HBINS; i += 256) dstp[i] = h[i];
}

// sum partials (coalesced slabs), emit cnt_in (scan input) + both dinv arrays
__global__ __launch_bounds__(256) void hist_reduce(const int* __restrict__ partA,  // src hist
                                                   const int* __restrict__ partB,  // dst hist
                                                   int* __restrict__ cnt_in,
                                                   float* __restrict__ dinv_out,
                                                   float* __restrict__ dinv_in, int n)
{
    const int i = blockIdx.x * 256 + threadIdx.x;
    if (i >= n) return;
    const int r = i >> 14, b = i & (HBINS - 1);
    const size_t base = ((size_t)r * HCHUNKS) * HBINS + b;
    int so = 0, si = 0;
    #pragma unroll
    for (int c = 0; c < HCHUNKS; ++c) {
        so += partA[base + (size_t)c * HBINS];
        si += partB[base + (size_t)c * HBINS];
    }
    dinv_out[i] = rsqrtf(fmaxf((float)so, 1.0f));
    dinv_in[i]  = rsqrtf(fmaxf((float)si, 1.0f));
    cnt_in[i] = si;
}

// ---------------- scan + fill (unchanged) ----------------

__global__ __launch_bounds__(256) void scan_partial(const int* __restrict__ cnt,
                                                    int* __restrict__ pre,
                                                    int* __restrict__ blk_sums, int n)
{
    __shared__ int lds[256];
    int t = threadIdx.x;
    int base = blockIdx.x * 1024 + t * 4;
    int v0 = 0, v1 = 0, v2 = 0, v3 = 0;
    if (base + 0 < n) v0 = cnt[base + 0];
    if (base + 1 < n) v1 = cnt[base + 1];
    if (base + 2 < n) v2 = cnt[base + 2];
    if (base + 3 < n) v3 = cnt[base + 3];
    int ts = v0 + v1 + v2 + v3;
    lds[t] = ts;
    __syncthreads();
    for (int off = 1; off < 256; off <<= 1) {
        int add = (t >= off) ? lds[t - off] : 0;
        __syncthreads();
        lds[t] += add;
        __syncthreads();
    }
    int excl = lds[t] - ts;
    if (base + 0 < n) pre[base + 0] = excl;
    if (base + 1 < n) pre[base + 1] = excl + v0;
    if (base + 2 < n) pre[base + 2] = excl + v0 + v1;
    if (base + 3 < n) pre[base + 3] = excl + v0 + v1 + v2;
    if (t == 255) blk_sums[blockIdx.x] = lds[255];
}

__global__ void scan_blk(const int* __restrict__ blk_sums, int* __restrict__ blk_off, int nblk)
{
    if (threadIdx.x == 0 && blockIdx.x == 0) {
        int run = 0;
        for (int j = 0; j < nblk; ++j) { blk_off[j] = run; run += blk_sums[j]; }
    }
}

__global__ __launch_bounds__(256) void scan_final(const int* __restrict__ pre,
                                                  const int* __restrict__ blk_off,
                                                  int* __restrict__ row_start,
                                                  int* __restrict__ fill_ptr, int n, int E)
{
    int i = blockIdx.x * 256 + threadIdx.x;
    if (i < n) {
        int v = pre[i] + blk_off[i >> 10];
        row_start[i] = v;
        fill_ptr[i]  = v;
    }
    if (i == 0) row_start[n] = E;
}

__global__ __launch_bounds__(256) void fill_kernel(const int* __restrict__ src,
                                                   const int* __restrict__ dst,
                                                   int* __restrict__ fill_ptr,
                                                   int* __restrict__ esrc, int E)
{
    int i = blockIdx.x * 256 + threadIdx.x;
    if (i < E) {
        int p = atomicAdd(&fill_ptr[dst[i]], 1);
        esrc[p] = src[i];
    }
}

// ---------------- weight transpose + f16 convert: Wt[n][k] = (f16)W[k][n] ----------------
__global__ __launch_bounds__(256) void wt_kernel(const float* __restrict__ W,
                                                 _Float16* __restrict__ Wt)
{
    __shared__ float tile[32][33];
    const int b = blockIdx.x;
    const int tx = b & 3, ty = b >> 2;          // 4x4 tiles of 32x32
    const int t = threadIdx.x;
    const int r = t >> 3, c4 = (t & 7) * 4;
    const float4 v = *(const float4*)&W[(size_t)(ty * 32 + r) * D + tx * 32 + c4];
    tile[r][c4 + 0] = v.x; tile[r][c4 + 1] = v.y;
    tile[r][c4 + 2] = v.z; tile[r][c4 + 3] = v.w;
    __syncthreads();
    _Float16* dst = Wt + (size_t)(tx * 32 + r) * D + ty * 32 + c4;
    dst[0] = (_Float16)tile[c4 + 0][r];
    dst[1] = (_Float16)tile[c4 + 1][r];
    dst[2] = (_Float16)tile[c4 + 2][r];
    dst[3] = (_Float16)tile[c4 + 3][r];
}

// ---------------- graph conv (f16 h, f32 rep) ----------------
// 16 lanes per node; 4 nodes per wave; edge loop unrolled x2 -> 8 gathers in
// flight per wave (round-11 measured: 162 -> <124us per layer).
__global__ __launch_bounds__(256, 4) void conv_f16(const _Float16* __restrict__ hin,
                                                   _Float16* __restrict__ hout,
                                                   float* __restrict__ rep,
                                                   const int* __restrict__ row_start,
                                                   const int* __restrict__ esrc,
                                                   const float* __restrict__ dinv_out,
                                                   const float* __restrict__ dinv_in,
                                                   const float* __restrict__ gamma,
                                                   int lidx, int n)
{
    const int node = (blockIdx.x * 256 + threadIdx.x) >> 4;
    const int sub  = threadIdx.x & 15;
    if (node >= n) return;
    const int rs = row_start[node];
    const int re = row_start[node + 1];
    const half8* hb = (const half8*)hin;

    float acc[8] = {0.f, 0.f, 0.f, 0.f, 0.f, 0.f, 0.f, 0.f};
    int i = rs;
    for (; i + 1 < re; i += 2) {
        const int s0 = esrc[i];
        const int s1 = esrc[i + 1];
        const float c0 = dinv_out[s0];
        const float c1 = dinv_out[s1];
        const half8 v0 = hb[(size_t)s0 * 16 + sub];
        const half8 v1 = hb[(size_t)s1 * 16 + sub];
        #pragma unroll
        for (int j = 0; j < 8; ++j)
            acc[j] += (float)v0[j] * c0 + (float)v1[j] * c1;
    }
    if (i < re) {
        const int s0 = esrc[i];
        const float c0 = dinv_out[s0];
        const half8 v0 = hb[(size_t)s0 * 16 + sub];
        #pragma unroll
        for (int j = 0; j < 8; ++j)
            acc[j] += (float)v0[j] * c0;
    }

    const float di = dinv_in[node];
    const float g  = gamma[lidx];
    half8 o;
    #pragma unroll
    for (int j = 0; j < 8; ++j) {
        acc[j] *= di;
        o[j] = (_Float16)acc[j];
    }
    ((half8*)hout)[(size_t)node * 16 + sub] = o;

    floatx4* rp = (floatx4*)(rep + (size_t)node * D + sub * 8);
    floatx4 r0 = rp[0], r1 = rp[1];
    r0[0] += g * acc[0]; r0[1] += g * acc[1]; r0[2] += g * acc[2]; r0[3] += g * acc[3];
    r1[0] += g * acc[4]; r1[1] += g * acc[5]; r1[2] += g * acc[6]; r1[3] += g * acc[7];
    rp[0] = r0; rp[1] = r1;
}

// ---------------- MFMA f16 GEMM: out[R x 128] = op(A) @ W + b ----------------
__device__ __forceinline__ int lds_off(int r, int chunk)
{
    return r * D + ((chunk ^ (r & 15)) << 3);
}

template<int MODE>
__global__ __launch_bounds__(256, 2) void gemm_mfma(const float* __restrict__ Xf,
                                                    const _Float16* __restrict__ Xh,
                                                    const _Float16* __restrict__ Wt,
                                                    const float* __restrict__ B, int R,
                                                    _Float16* __restrict__ outh,
                                                    float* __restrict__ rep,
                                                    const float* __restrict__ gamma,
                                                    const int* __restrict__ ia,
                                                    const int* __restrict__ ib,
                                                    const float* __restrict__ w3,
                                                    const float* __restrict__ b3,
                                                    float* __restrict__ outsc)
{
    __shared__ _Float16 Als[D * D];
    __shared__ _Float16 Wls[D * D];
    const int t = threadIdx.x;
    const int rowbase = blockIdx.x * D;

    #pragma unroll
    for (int it = 0; it < 8; ++it) {
        const int r = it * 16 + (t >> 4);
        const int c = t & 15;
        *(half8*)&Wls[lds_off(r, c)] = *(const half8*)(Wt + (size_t)r * D + c * 8);
        int g = rowbase + r; if (g > R - 1) g = R - 1;
        half8 hv;
        if (MODE == 0) {
            const float4* ap = (const float4*)(Xf + (size_t)g * D + c * 8);
            float4 a0 = ap[0], a1 = ap[1];
            hv[0] = (_Float16)a0.x; hv[1] = (_Float16)a0.y;
            hv[2] = (_Float16)a0.z; hv[3] = (_Float16)a0.w;
            hv[4] = (_Float16)a1.x; hv[5] = (_Float16)a1.y;
            hv[6] = (_Float16)a1.z; hv[7] = (_Float16)a1.w;
        } else if (MODE == 2) {
            const float4* pa = (const float4*)(Xf + (size_t)ia[g] * D + c * 8);
            const float4* pb = (const float4*)(Xf + (size_t)ib[g] * D + c * 8);
            float4 a0 = pa[0], a1 = pa[1], b0 = pb[0], b1 = pb[1];
            hv[0] = (_Float16)(a0.x * b0.x); hv[1] = (_Float16)(a0.y * b0.y);
            hv[2] = (_Float16)(a0.z * b0.z); hv[3] = (_Float16)(a0.w * b0.w);
            hv[4] = (_Float16)(a1.x * b1.x); hv[5] = (_Float16)(a1.y * b1.y);
            hv[6] = (_Float16)(a1.z * b1.z); hv[7] = (_Float16)(a1.w * b1.w);
        } else {
            hv = *(const half8*)(Xh + (size_t)g * D + c * 8);
        }
        *(half8*)&Als[lds_off(r, c)] = hv;
    }
    __syncthreads();

    const int wid = t >> 6;
    const int l   = t & 63;
    const int lr  = l & 15;
    const int lq  = l >> 4;

    floatx4 acc[2][8];
    #pragma unroll
    for (int m = 0; m < 2; ++m)
        #pragma unroll
        for (int n = 0; n < 8; ++n) {
            acc[m][n][0] = 0.f; acc[m][n][1] = 0.f;
            acc[m][n][2] = 0.f; acc[m][n][3] = 0.f;
        }

    #pragma unroll
    for (int kk = 0; kk < 4; ++kk) {
        const int cc = kk * 4 + lq;
        half8 af[2], bf[8];
        #pragma unroll
        for (int m = 0; m < 2; ++m) {
            const int r = wid * 32 + m * 16 + lr;
            af[m] = *(half8*)&Als[lds_off(r, cc)];
        }
        #pragma unroll
        for (int n = 0; n < 8; ++n) {
            const int r = n * 16 + lr;
            bf[n] = *(half8*)&Wls[lds_off(r, cc)];
        }
        #pragma unroll
        for (int m = 0; m < 2; ++m)
            #pragma unroll
            for (int n = 0; n < 8; ++n)
                acc[m][n] = __builtin_amdgcn_mfma_f32_16x16x32_f16(af[m], bf[n], acc[m][n], 0, 0, 0);
    }

    // C/D layout: col = lane&15, row = (lane>>4)*4 + reg
    if (MODE == 3) {
        float bv[8], wv[8];
        #pragma unroll
        for (int n = 0; n < 8; ++n) { bv[n] = B[n * 16 + lr]; wv[n] = w3[n * 16 + lr]; }
        const float bb = b3[0];
        #pragma unroll
        for (int m = 0; m < 2; ++m) {
            #pragma unroll
            for (int q = 0; q < 4; ++q) {
                float s = 0.f;
                #pragma unroll
                for (int n = 0; n < 8; ++n)
                    s += fmaxf(acc[m][n][q] + bv[n], 0.f) * wv[n];
                s += __shfl_xor(s, 1); s += __shfl_xor(s, 2);
                s += __shfl_xor(s, 4); s += __shfl_xor(s, 8);
                const int r = rowbase + wid * 32 + m * 16 + lq * 4 + q;
                if (lr == 0 && r < R) outsc[r] = s + bb;
            }
        }
    } else {
        float bv[8];
        #pragma unroll
        for (int n = 0; n < 8; ++n) bv[n] = B[n * 16 + lr];
        const float g0 = (MODE == 1) ? gamma[0] : 0.f;
        #pragma unroll
        for (int m = 0; m < 2; ++m) {
            #pragma unroll
            for (int q = 0; q < 4; ++q) {
                const int r = rowbase + wid * 32 + m * 16 + lq * 4 + q;
                if (r < R) {
                    #pragma unroll
                    for (int n = 0; n < 8; ++n) {
                        float v = acc[m][n][q] + bv[n];
                        if (MODE != 1) v = fmaxf(v, 0.f);
                        outh[(size_t)r * D + n * 16 + lr] = (_Float16)v;
                        if (MODE == 1) rep[(size_t)r * D + n * 16 + lr] = g0 * v;
                    }
                }
            }
        }
    }
}

// ---------------- launcher ----------------

extern "C" void kernel_launch(void* const* d_in, const int* in_sizes, int n_in,
                              void* d_out, int out_size, void* d_ws, size_t ws_size,
                              hipStream_t stream)
{
    const float* x      = (const float*)d_in[0];
    const float* lin1_w = (const float*)d_in[1];
    const float* lin1_b = (const float*)d_in[2];
    const float* lin2_w = (const float*)d_in[3];
    const float* lin2_b = (const float*)d_in[4];
    const float* gamma  = (const float*)d_in[5];
    const float* p1_w   = (const float*)d_in[6];
    const float* p1_b   = (const float*)d_in[7];
    const float* p2_w   = (const float*)d_in[8];
    const float* p2_b   = (const float*)d_in[9];
    const float* p3_w   = (const float*)d_in[10];
    const float* p3_b   = (const float*)d_in[11];
    const int* src     = (const int*)d_in[12];
    const int* dst     = (const int*)d_in[13];
    const int* pos_src = (const int*)d_in[14];
    const int* pos_dst = (const int*)d_in[15];
    const int* neg_src = (const int*)d_in[16];
    const int* neg_dst = (const int*)d_in[17];

    const int N = in_sizes[0] / D;
    const int E = in_sizes[12];
    const int P = in_sizes[14];
    const int NR = cdiv(N, HBINS);               // node ranges for histogram

    char* base = (char*)d_ws;
    _Float16* bufB = (_Float16*)base;                    // h1 (f16)
    _Float16* bufA = bufB + (size_t)N * D;               // h0 / conv pong (f16)
    float*    rep  = (float*)(bufA + (size_t)N * D);     // f32 accumulation
    _Float16* wt1  = (_Float16*)(rep + (size_t)N * D);
    _Float16* wt2  = wt1 + D * D;
    _Float16* wtp1 = wt2 + D * D;
    _Float16* wtp2 = wtp1 + D * D;
    char* ip = (char*)(wtp2 + D * D);
    int* cnt_in    = (int*)ip;  ip += (size_t)N * 4;
    int* pre       = (int*)ip;  ip += (size_t)N * 4;
    int* row_start = (int*)ip;  ip += (size_t)(N + 1) * 4;
    int* fill_ptr  = (int*)ip;  ip += (size_t)N * 4;
    int* blk_sums  = (int*)ip;  ip += 4096 * 4;
    int* blk_off   = (int*)ip;  ip += 4096 * 4;
    float* dinv_out = (float*)ip; ip += (size_t)N * 4;
    float* dinv_in  = (float*)ip; ip += (size_t)N * 4;
    int* esrc      = (int*)ip;  ip += (size_t)E * 4;
    int* partA     = (int*)ip;  ip += (size_t)NR * HCHUNKS * HBINS * 4;
    int* partB     = (int*)ip;  ip += (size_t)NR * HCHUNKS * HBINS * 4;
    _Float16* e1;
    if ((size_t)(2 * P) <= 2 * (size_t)N) {
        e1 = (_Float16*)base;
    } else {
        e1 = (_Float16*)ip; ip += (size_t)(2 * P) * D * 2;
    }

    // ---- degrees (LDS-privatized histograms, no global atomics) + CSR ----
    hist_kernel<<<NR * HCHUNKS, 256, 0, stream>>>(src, E, partA);
    hist_kernel<<<NR * HCHUNKS, 256, 0, stream>>>(dst, E, partB);
    hist_reduce<<<cdiv(N, 256), 256, 0, stream>>>(partA, partB, cnt_in,
                                                  dinv_out, dinv_in, N);
    int nblk = cdiv(N, 1024);
    scan_partial<<<nblk, 256, 0, stream>>>(cnt_in, pre, blk_sums, N);
    scan_blk<<<1, 64, 0, stream>>>(blk_sums, blk_off, nblk);
    scan_final<<<cdiv(N, 256), 256, 0, stream>>>(pre, blk_off, row_start, fill_ptr, N, E);
    fill_kernel<<<cdiv(E, 256), 256, 0, stream>>>(src, dst, fill_ptr, esrc, E);

    // ---- weight transpose + f16 ----
    wt_kernel<<<16, 256, 0, stream>>>(lin1_w, wt1);
    wt_kernel<<<16, 256, 0, stream>>>(lin2_w, wt2);
    wt_kernel<<<16, 256, 0, stream>>>(p1_w, wtp1);
    wt_kernel<<<16, 256, 0, stream>>>(p2_w, wtp2);

    // ---- node MLP ----
    gemm_mfma<0><<<cdiv(N, 128), 256, 0, stream>>>(x, nullptr, wt1, lin1_b, N,
        bufB, nullptr, nullptr, nullptr, nullptr, nullptr, nullptr, nullptr);
    gemm_mfma<1><<<cdiv(N, 128), 256, 0, stream>>>(nullptr, bufB, wt2, lin2_b, N,
        bufA, rep, gamma, nullptr, nullptr, nullptr, nullptr, nullptr);

    // ---- 3 propagation layers ----
    conv_f16<<<cdiv(N * 16, 256), 256, 0, stream>>>(bufA, bufB, rep, row_start, esrc,
                                                    dinv_out, dinv_in, gamma, 1, N);
    conv_f16<<<cdiv(N * 16, 256), 256, 0, stream>>>(bufB, bufA, rep, row_start, esrc,
                                                    dinv_out, dinv_in, gamma, 2, N);
    conv_f16<<<cdiv(N * 16, 256), 256, 0, stream>>>(bufA, bufB, rep, row_start, esrc,
                                                    dinv_out, dinv_in, gamma, 3, N);

    // ---- predictor ----
    gemm_mfma<2><<<cdiv(P, 128), 256, 0, stream>>>(rep, nullptr, wtp1, p1_b, P,
        e1, nullptr, nullptr, pos_src, pos_dst, nullptr, nullptr, nullptr);
    gemm_mfma<2><<<cdiv(P, 128), 256, 0, stream>>>(rep, nullptr, wtp1, p1_b, P,
        e1 + (size_t)P * D, nullptr, nullptr, neg_src, neg_dst, nullptr, nullptr, nullptr);
    gemm_mfma<3><<<cdiv(2 * P, 128), 256, 0, stream>>>(nullptr, e1, wtp2, p2_b, 2 * P,
        nullptr, nullptr, nullptr, nullptr, nullptr, p3_w, p3_b, (float*)d_out);
}

// Round 14
// 572.950 us; speedup vs baseline: 2.8097x; 1.1208x over previous
//
#include <hip/hip_runtime.h>

#define D 128
#define HBINS 16384      // 2^14 bins = 64 KB LDS histogram per block
#define HCHUNKS 32       // edge chunks per node-range

typedef _Float16 half8 __attribute__((ext_vector_type(8)));
typedef float floatx4 __attribute__((ext_vector_type(4)));

__host__ __device__ static inline int cdiv(int a, int b){ return (a + b - 1) / b; }

// ---------------- no-atomic degree histograms ----------------
__global__ __launch_bounds__(256) void hist_kernel(const int* __restrict__ vals, int E,
                                                   int* __restrict__ part)
{
    __shared__ int h[HBINS];
    const int r = blockIdx.x / HCHUNKS;
    const int c = blockIdx.x % HCHUNKS;
    for (int i = threadIdx.x; i < HBINS; i += 256) h[i] = 0;
    __syncthreads();

    int elen = cdiv(E, HCHUNKS);
    elen = (elen + 3) & ~3;
    const int lo = c * elen;
    const int hi = min(E, lo + elen);
    if (lo < hi) {
        const int nfull = (hi - lo) >> 2;
        const int4* v4 = (const int4*)(vals + lo);
        for (int i = threadIdx.x; i < nfull; i += 256) {
            const int4 v = v4[i];
            if ((v.x >> 14) == r) atomicAdd(&h[v.x & (HBINS - 1)], 1);
            if ((v.y >> 14) == r) atomicAdd(&h[v.y & (HBINS - 1)], 1);
            if ((v.z >> 14) == r) atomicAdd(&h[v.z & (HBINS - 1)], 1);
            if ((v.w >> 14) == r) atomicAdd(&h[v.w & (HBINS - 1)], 1);
        }
        for (int i = lo + (nfull << 2) + threadIdx.x; i < hi; i += 256) {
            const int v = vals[i];
            if ((v >> 14) == r) atomicAdd(&h[v & (HBINS - 1)], 1);
        }
    }
    __syncthreads();
    int* dstp = part + (size_t)blockIdx.x * HBINS;
    for (int i = threadIdx.x; i < HBINS; i += 256) dstp[i] = h[i];
}

// sum partials (coalesced slabs), emit cnt_in (scan input) + both dinv arrays
__global__ __launch_bounds__(256) void hist_reduce(const int* __restrict__ partA,
                                                   const int* __restrict__ partB,
                                                   int* __restrict__ cnt_in,
                                                   float* __restrict__ dinv_out,
                                                   float* __restrict__ dinv_in, int n)
{
    const int i = blockIdx.x * 256 + threadIdx.x;
    if (i >= n) return;
    const int r = i >> 14, b = i & (HBINS - 1);
    const size_t base = ((size_t)r * HCHUNKS) * HBINS + b;
    int so = 0, si = 0;
    #pragma unroll
    for (int c = 0; c < HCHUNKS; ++c) {
        so += partA[base + (size_t)c * HBINS];
        si += partB[base + (size_t)c * HBINS];
    }
    dinv_out[i] = rsqrtf(fmaxf((float)so, 1.0f));
    dinv_in[i]  = rsqrtf(fmaxf((float)si, 1.0f));
    cnt_in[i] = si;
}

// ---------------- scan ----------------

__global__ __launch_bounds__(256) void scan_partial(const int* __restrict__ cnt,
                                                    int* __restrict__ pre,
                                                    int* __restrict__ blk_sums, int n)
{
    __shared__ int lds[256];
    int t = threadIdx.x;
    int base = blockIdx.x * 1024 + t * 4;
    int v0 = 0, v1 = 0, v2 = 0, v3 = 0;
    if (base + 0 < n) v0 = cnt[base + 0];
    if (base + 1 < n) v1 = cnt[base + 1];
    if (base + 2 < n) v2 = cnt[base + 2];
    if (base + 3 < n) v3 = cnt[base + 3];
    int ts = v0 + v1 + v2 + v3;
    lds[t] = ts;
    __syncthreads();
    for (int off = 1; off < 256; off <<= 1) {
        int add = (t >= off) ? lds[t - off] : 0;
        __syncthreads();
        lds[t] += add;
        __syncthreads();
    }
    int excl = lds[t] - ts;
    if (base + 0 < n) pre[base + 0] = excl;
    if (base + 1 < n) pre[base + 1] = excl + v0;
    if (base + 2 < n) pre[base + 2] = excl + v0 + v1;
    if (base + 3 < n) pre[base + 3] = excl + v0 + v1 + v2;
    if (t == 255) blk_sums[blockIdx.x] = lds[255];
}

__global__ void scan_blk(const int* __restrict__ blk_sums, int* __restrict__ blk_off, int nblk)
{
    if (threadIdx.x == 0 && blockIdx.x == 0) {
        int run = 0;
        for (int j = 0; j < nblk; ++j) { blk_off[j] = run; run += blk_sums[j]; }
    }
}

__global__ __launch_bounds__(256) void scan_final(const int* __restrict__ pre,
                                                  const int* __restrict__ blk_off,
                                                  int* __restrict__ row_start, int n, int E)
{
    int i = blockIdx.x * 256 + threadIdx.x;
    if (i < n) row_start[i] = pre[i] + blk_off[i >> 10];
    if (i == 0) row_start[n] = E;
}

// ---------------- counting-sort placement (no global atomics) ----------------
// cbase[r][c][bin] = row_start[node] + sum_{c'<c} partB[r][c'][bin]
__global__ __launch_bounds__(256) void cbase_kernel(const int* __restrict__ partB,
                                                    const int* __restrict__ row_start,
                                                    int* __restrict__ cb, int n)
{
    const int i = blockIdx.x * 256 + threadIdx.x;
    if (i >= n) return;
    const int r = i >> 14, b = i & (HBINS - 1);
    const size_t base = ((size_t)r * HCHUNKS) * HBINS + b;
    int run = row_start[i];
    #pragma unroll
    for (int c = 0; c < HCHUNKS; ++c) {
        cb[base + (size_t)c * HBINS] = run;
        run += partB[base + (size_t)c * HBINS];
    }
}

// block (r,c): LDS cursors from cbase slab; stream chunk; LDS-atomic place.
// Chunk bounds identical to hist_kernel => slices tile each CSR row exactly.
__global__ __launch_bounds__(256) void fill_hist(const int* __restrict__ src,
                                                 const int* __restrict__ dst,
                                                 const int* __restrict__ cb,
                                                 int* __restrict__ esrc, int E)
{
    __shared__ int h[HBINS];
    const int r = blockIdx.x / HCHUNKS;
    const int c = blockIdx.x % HCHUNKS;
    const int* cbs = cb + (size_t)blockIdx.x * HBINS;
    for (int i = threadIdx.x; i < HBINS; i += 256) h[i] = cbs[i];
    __syncthreads();

    int elen = cdiv(E, HCHUNKS);
    elen = (elen + 3) & ~3;
    const int lo = c * elen;
    const int hi = min(E, lo + elen);
    if (lo >= hi) return;
    const int nfull = (hi - lo) >> 2;
    const int4* d4 = (const int4*)(dst + lo);
    const int4* s4 = (const int4*)(src + lo);
    for (int i = threadIdx.x; i < nfull; i += 256) {
        const int4 dv = d4[i];
        const int4 sv = s4[i];
        if ((dv.x >> 14) == r) { int p = atomicAdd(&h[dv.x & (HBINS - 1)], 1); esrc[p] = sv.x; }
        if ((dv.y >> 14) == r) { int p = atomicAdd(&h[dv.y & (HBINS - 1)], 1); esrc[p] = sv.y; }
        if ((dv.z >> 14) == r) { int p = atomicAdd(&h[dv.z & (HBINS - 1)], 1); esrc[p] = sv.z; }
        if ((dv.w >> 14) == r) { int p = atomicAdd(&h[dv.w & (HBINS - 1)], 1); esrc[p] = sv.w; }
    }
    for (int i = lo + (nfull << 2) + threadIdx.x; i < hi; i += 256) {
        const int dv = dst[i];
        if ((dv >> 14) == r) { int p = atomicAdd(&h[dv & (HBINS - 1)], 1); esrc[p] = src[i]; }
    }
}

// ---------------- weight transpose + f16 convert: Wt[n][k] = (f16)W[k][n] ----------------
__global__ __launch_bounds__(256) void wt_kernel(const float* __restrict__ W,
                                                 _Float16* __restrict__ Wt)
{
    __shared__ float tile[32][33];
    const int b = blockIdx.x;
    const int tx = b & 3, ty = b >> 2;          // 4x4 tiles of 32x32
    const int t = threadIdx.x;
    const int r = t >> 3, c4 = (t & 7) * 4;
    const float4 v = *(const float4*)&W[(size_t)(ty * 32 + r) * D + tx * 32 + c4];
    tile[r][c4 + 0] = v.x; tile[r][c4 + 1] = v.y;
    tile[r][c4 + 2] = v.z; tile[r][c4 + 3] = v.w;
    __syncthreads();
    _Float16* dst = Wt + (size_t)(tx * 32 + r) * D + ty * 32 + c4;
    dst[0] = (_Float16)tile[c4 + 0][r];
    dst[1] = (_Float16)tile[c4 + 1][r];
    dst[2] = (_Float16)tile[c4 + 2][r];
    dst[3] = (_Float16)tile[c4 + 3][r];
}

// ---------------- graph conv (f16 h, f32 rep) ----------------
__global__ __launch_bounds__(256, 4) void conv_f16(const _Float16* __restrict__ hin,
                                                   _Float16* __restrict__ hout,
                                                   float* __restrict__ rep,
                                                   const int* __restrict__ row_start,
                                                   const int* __restrict__ esrc,
                                                   const float* __restrict__ dinv_out,
                                                   const float* __restrict__ dinv_in,
                                                   const float* __restrict__ gamma,
                                                   int lidx, int n)
{
    const int node = (blockIdx.x * 256 + threadIdx.x) >> 4;
    const int sub  = threadIdx.x & 15;
    if (node >= n) return;
    const int rs = row_start[node];
    const int re = row_start[node + 1];
    const half8* hb = (const half8*)hin;

    float acc[8] = {0.f, 0.f, 0.f, 0.f, 0.f, 0.f, 0.f, 0.f};
    int i = rs;
    for (; i + 1 < re; i += 2) {
        const int s0 = esrc[i];
        const int s1 = esrc[i + 1];
        const float c0 = dinv_out[s0];
        const float c1 = dinv_out[s1];
        const half8 v0 = hb[(size_t)s0 * 16 + sub];
        const half8 v1 = hb[(size_t)s1 * 16 + sub];
        #pragma unroll
        for (int j = 0; j < 8; ++j)
            acc[j] += (float)v0[j] * c0 + (float)v1[j] * c1;
    }
    if (i < re) {
        const int s0 = esrc[i];
        const float c0 = dinv_out[s0];
        const half8 v0 = hb[(size_t)s0 * 16 + sub];
        #pragma unroll
        for (int j = 0; j < 8; ++j)
            acc[j] += (float)v0[j] * c0;
    }

    const float di = dinv_in[node];
    const float g  = gamma[lidx];
    half8 o;
    #pragma unroll
    for (int j = 0; j < 8; ++j) {
        acc[j] *= di;
        o[j] = (_Float16)acc[j];
    }
    ((half8*)hout)[(size_t)node * 16 + sub] = o;

    floatx4* rp = (floatx4*)(rep + (size_t)node * D + sub * 8);
    floatx4 r0 = rp[0], r1 = rp[1];
    r0[0] += g * acc[0]; r0[1] += g * acc[1]; r0[2] += g * acc[2]; r0[3] += g * acc[3];
    r1[0] += g * acc[4]; r1[1] += g * acc[5]; r1[2] += g * acc[6]; r1[3] += g * acc[7];
    rp[0] = r0; rp[1] = r1;
}

// ---------------- MFMA f16 GEMM: out[R x 128] = op(A) @ W + b ----------------
__device__ __forceinline__ int lds_off(int r, int chunk)
{
    return r * D + ((chunk ^ (r & 15)) << 3);
}

template<int MODE>
__global__ __launch_bounds__(256, 2) void gemm_mfma(const float* __restrict__ Xf,
                                                    const _Float16* __restrict__ Xh,
                                                    const _Float16* __restrict__ Wt,
                                                    const float* __restrict__ B, int R,
                                                    _Float16* __restrict__ outh,
                                                    float* __restrict__ rep,
                                                    const float* __restrict__ gamma,
                                                    const int* __restrict__ ia,
                                                    const int* __restrict__ ib,
                                                    const float* __restrict__ w3,
                                                    const float* __restrict__ b3,
                                                    float* __restrict__ outsc)
{
    __shared__ _Float16 Als[D * D];
    __shared__ _Float16 Wls[D * D];
    const int t = threadIdx.x;
    const int rowbase = blockIdx.x * D;

    #pragma unroll
    for (int it = 0; it < 8; ++it) {
        const int r = it * 16 + (t >> 4);
        const int c = t & 15;
        *(half8*)&Wls[lds_off(r, c)] = *(const half8*)(Wt + (size_t)r * D + c * 8);
        int g = rowbase + r; if (g > R - 1) g = R - 1;
        half8 hv;
        if (MODE == 0) {
            const float4* ap = (const float4*)(Xf + (size_t)g * D + c * 8);
            float4 a0 = ap[0], a1 = ap[1];
            hv[0] = (_Float16)a0.x; hv[1] = (_Float16)a0.y;
            hv[2] = (_Float16)a0.z; hv[3] = (_Float16)a0.w;
            hv[4] = (_Float16)a1.x; hv[5] = (_Float16)a1.y;
            hv[6] = (_Float16)a1.z; hv[7] = (_Float16)a1.w;
        } else if (MODE == 2) {
            const float4* pa = (const float4*)(Xf + (size_t)ia[g] * D + c * 8);
            const float4* pb = (const float4*)(Xf + (size_t)ib[g] * D + c * 8);
            float4 a0 = pa[0], a1 = pa[1], b0 = pb[0], b1 = pb[1];
            hv[0] = (_Float16)(a0.x * b0.x); hv[1] = (_Float16)(a0.y * b0.y);
            hv[2] = (_Float16)(a0.z * b0.z); hv[3] = (_Float16)(a0.w * b0.w);
            hv[4] = (_Float16)(a1.x * b1.x); hv[5] = (_Float16)(a1.y * b1.y);
            hv[6] = (_Float16)(a1.z * b1.z); hv[7] = (_Float16)(a1.w * b1.w);
        } else {
            hv = *(const half8*)(Xh + (size_t)g * D + c * 8);
        }
        *(half8*)&Als[lds_off(r, c)] = hv;
    }
    __syncthreads();

    const int wid = t >> 6;
    const int l   = t & 63;
    const int lr  = l & 15;
    const int lq  = l >> 4;

    floatx4 acc[2][8];
    #pragma unroll
    for (int m = 0; m < 2; ++m)
        #pragma unroll
        for (int n = 0; n < 8; ++n) {
            acc[m][n][0] = 0.f; acc[m][n][1] = 0.f;
            acc[m][n][2] = 0.f; acc[m][n][3] = 0.f;
        }

    #pragma unroll
    for (int kk = 0; kk < 4; ++kk) {
        const int cc = kk * 4 + lq;
        half8 af[2], bf[8];
        #pragma unroll
        for (int m = 0; m < 2; ++m) {
            const int r = wid * 32 + m * 16 + lr;
            af[m] = *(half8*)&Als[lds_off(r, cc)];
        }
        #pragma unroll
        for (int n = 0; n < 8; ++n) {
            const int r = n * 16 + lr;
            bf[n] = *(half8*)&Wls[lds_off(r, cc)];
        }
        #pragma unroll
        for (int m = 0; m < 2; ++m)
            #pragma unroll
            for (int n = 0; n < 8; ++n)
                acc[m][n] = __builtin_amdgcn_mfma_f32_16x16x32_f16(af[m], bf[n], acc[m][n], 0, 0, 0);
    }

    // C/D layout: col = lane&15, row = (lane>>4)*4 + reg
    if (MODE == 3) {
        float bv[8], wv[8];
        #pragma unroll
        for (int n = 0; n < 8; ++n) { bv[n] = B[n * 16 + lr]; wv[n] = w3[n * 16 + lr]; }
        const float bb = b3[0];
        #pragma unroll
        for (int m = 0; m < 2; ++m) {
            #pragma unroll
            for (int q = 0; q < 4; ++q) {
                float s = 0.f;
                #pragma unroll
                for (int n = 0; n < 8; ++n)
                    s += fmaxf(acc[m][n][q] + bv[n], 0.f) * wv[n];
                s += __shfl_xor(s, 1); s += __shfl_xor(s, 2);
                s += __shfl_xor(s, 4); s += __shfl_xor(s, 8);
                const int r = rowbase + wid * 32 + m * 16 + lq * 4 + q;
                if (lr == 0 && r < R) outsc[r] = s + bb;
            }
        }
    } else {
        float bv[8];
        #pragma unroll
        for (int n = 0; n < 8; ++n) bv[n] = B[n * 16 + lr];
        const float g0 = (MODE == 1) ? gamma[0] : 0.f;
        #pragma unroll
        for (int m = 0; m < 2; ++m) {
            #pragma unroll
            for (int q = 0; q < 4; ++q) {
                const int r = rowbase + wid * 32 + m * 16 + lq * 4 + q;
                if (r < R) {
                    #pragma unroll
                    for (int n = 0; n < 8; ++n) {
                        float v = acc[m][n][q] + bv[n];
                        if (MODE != 1) v = fmaxf(v, 0.f);
                        outh[(size_t)r * D + n * 16 + lr] = (_Float16)v;
                        if (MODE == 1) rep[(size_t)r * D + n * 16 + lr] = g0 * v;
                    }
                }
            }
        }
    }
}

// ---------------- launcher ----------------

extern "C" void kernel_launch(void* const* d_in, const int* in_sizes, int n_in,
                              void* d_out, int out_size, void* d_ws, size_t ws_size,
                              hipStream_t stream)
{
    const float* x      = (const float*)d_in[0];
    const float* lin1_w = (const float*)d_in[1];
    const float* lin1_b = (const float*)d_in[2];
    const float* lin2_w = (const float*)d_in[3];
    const float* lin2_b = (const float*)d_in[4];
    const float* gamma  = (const float*)d_in[5];
    const float* p1_w   = (const float*)d_in[6];
    const float* p1_b   = (const float*)d_in[7];
    const float* p2_w   = (const float*)d_in[8];
    const float* p2_b   = (const float*)d_in[9];
    const float* p3_w   = (const float*)d_in[10];
    const float* p3_b   = (const float*)d_in[11];
    const int* src     = (const int*)d_in[12];
    const int* dst     = (const int*)d_in[13];
    const int* pos_src = (const int*)d_in[14];
    const int* pos_dst = (const int*)d_in[15];
    const int* neg_src = (const int*)d_in[16];
    const int* neg_dst = (const int*)d_in[17];

    const int N = in_sizes[0] / D;
    const int E = in_sizes[12];
    const int P = in_sizes[14];
    const int NR = cdiv(N, HBINS);               // node ranges for histogram

    char* base = (char*)d_ws;
    _Float16* bufB = (_Float16*)base;                    // h1 (f16)
    _Float16* bufA = bufB + (size_t)N * D;               // h0 / conv pong (f16)
    float*    rep  = (float*)(bufA + (size_t)N * D);     // f32 accumulation
    _Float16* wt1  = (_Float16*)(rep + (size_t)N * D);
    _Float16* wt2  = wt1 + D * D;
    _Float16* wtp1 = wt2 + D * D;
    _Float16* wtp2 = wtp1 + D * D;
    char* ip = (char*)(wtp2 + D * D);
    int* cnt_in    = (int*)ip;  ip += (size_t)N * 4;
    int* pre       = (int*)ip;  ip += (size_t)N * 4;
    int* row_start = (int*)ip;  ip += (size_t)(N + 1) * 4;
    int* blk_sums  = (int*)ip;  ip += 4096 * 4;
    int* blk_off   = (int*)ip;  ip += 4096 * 4;
    float* dinv_out = (float*)ip; ip += (size_t)N * 4;
    float* dinv_in  = (float*)ip; ip += (size_t)N * 4;
    int* esrc      = (int*)ip;  ip += (size_t)E * 4;
    int* partA     = (int*)ip;  ip += (size_t)NR * HCHUNKS * HBINS * 4;
    int* partB     = (int*)ip;  ip += (size_t)NR * HCHUNKS * HBINS * 4;
    int* cbase     = (int*)ip;  ip += (size_t)NR * HCHUNKS * HBINS * 4;
    _Float16* e1;
    if ((size_t)(2 * P) <= 2 * (size_t)N) {
        e1 = (_Float16*)base;
    } else {
        e1 = (_Float16*)ip; ip += (size_t)(2 * P) * D * 2;
    }

    // ---- degrees + CSR (no global atomics anywhere) ----
    hist_kernel<<<NR * HCHUNKS, 256, 0, stream>>>(src, E, partA);
    hist_kernel<<<NR * HCHUNKS, 256, 0, stream>>>(dst, E, partB);
    hist_reduce<<<cdiv(N, 256), 256, 0, stream>>>(partA, partB, cnt_in,
                                                  dinv_out, dinv_in, N);
    int nblk = cdiv(N, 1024);
    scan_partial<<<nblk, 256, 0, stream>>>(cnt_in, pre, blk_sums, N);
    scan_blk<<<1, 64, 0, stream>>>(blk_sums, blk_off, nblk);
    scan_final<<<cdiv(N, 256), 256, 0, stream>>>(pre, blk_off, row_start, N, E);
    cbase_kernel<<<cdiv(N, 256), 256, 0, stream>>>(partB, row_start, cbase, N);
    fill_hist<<<NR * HCHUNKS, 256, 0, stream>>>(src, dst, cbase, esrc, E);

    // ---- weight transpose + f16 ----
    wt_kernel<<<16, 256, 0, stream>>>(lin1_w, wt1);
    wt_kernel<<<16, 256, 0, stream>>>(lin2_w, wt2);
    wt_kernel<<<16, 256, 0, stream>>>(p1_w, wtp1);
    wt_kernel<<<16, 256, 0, stream>>>(p2_w, wtp2);

    // ---- node MLP ----
    gemm_mfma<0><<<cdiv(N, 128), 256, 0, stream>>>(x, nullptr, wt1, lin1_b, N,
        bufB, nullptr, nullptr, nullptr, nullptr, nullptr, nullptr, nullptr);
    gemm_mfma<1><<<cdiv(N, 128), 256, 0, stream>>>(nullptr, bufB, wt2, lin2_b, N,
        bufA, rep, gamma, nullptr, nullptr, nullptr, nullptr, nullptr);

    // ---- 3 propagation layers ----
    conv_f16<<<cdiv(N * 16, 256), 256, 0, stream>>>(bufA, bufB, rep, row_start, esrc,
                                                    dinv_out, dinv_in, gamma, 1, N);
    conv_f16<<<cdiv(N * 16, 256), 256, 0, stream>>>(bufB, bufA, rep, row_start, esrc,
                                                    dinv_out, dinv_in, gamma, 2, N);
    conv_f16<<<cdiv(N * 16, 256), 256, 0, stream>>>(bufA, bufB, rep, row_start, esrc,
                                                    dinv_out, dinv_in, gamma, 3, N);

    // ---- predictor ----
    gemm_mfma<2><<<cdiv(P, 128), 256, 0, stream>>>(rep, nullptr, wtp1, p1_b, P,
        e1, nullptr, nullptr, pos_src, pos_dst, nullptr, nullptr, nullptr);
    gemm_mfma<2><<<cdiv(P, 128), 256, 0, stream>>>(rep, nullptr, wtp1, p1_b, P,
        e1 + (size_t)P * D, nullptr, nullptr, neg_src, neg_dst, nullptr, nullptr, nullptr);
    gemm_mfma<3><<<cdiv(2 * P, 128), 256, 0, stream>>>(nullptr, e1, wtp2, p2_b, 2 * P,
        nullptr, nullptr, nullptr, nullptr, nullptr, p3_w, p3_b, (float*)d_out);
}